// Round 14
// baseline (388.906 us; speedup 1.0000x reference)
//
#include <hip/hip_runtime.h>
#include <hip/hip_fp16.h>

#define NN 50000
#define NE 800000
// IN_C=16, EDGE_IN=16, HID=32, HEADS=4, HC=128
#define NB 196            // coarse buckets = ceil(NN/256)
#define EPB 3125          // edges per bucket-build block (NE/256)
#define NODE_BLOCKS 12500 // NN/4

// scale folded into all alpha components: log2(e)/sqrt(32)
#define SL 0.25506413f

// packed table offsets (floats)
#define PMV 0       // 1024: y table, lane-major [lane][i]
#define MEV 1024    // 1024: qe table
#define BEV 2048    // 64
#define UPV 2112    // 64
#define WPV 2176    // 64
#define WCV 2240    // 4
#define WPK 2244    // pad to 16B boundary below; actual offsets defined next
// re-align: start vector tables at 2304 (16B aligned in floats: mult of 4)
#define WPK4 2304   // 4096: per-lane {We_lo,We_hi,Wv_lo,Wv_hi} x16 (float4)
#define BVK  6400   // 128: per-lane {bv_lo, bv_hi} (float2)
#define WSPK 6528   // 512: per-t16 {Wskip[2k][t],Wskip[2k][t+16],Wskip[2k+1][t],Wskip[2k+1][t+16]} x8
#define BSK  7040   // 32: per-t {bskip[t], bskip[t+16]} (float2)
#define W1PK 7072   // 2048: per-lane W1 A/C columns x8 (float4)
#define P_TOTAL 9120

// DPP-based add over lanes: quad xor1=0xB1, xor2=0x4E, row_ror:4=0x124,
// row_ror:8=0x128 (rows are 16 lanes = one head group). VALU-pipe only.
template <int CTRL>
__device__ __forceinline__ float dpp_add(float v) {
  int m = __builtin_amdgcn_update_dpp(0, __builtin_bit_cast(int, v), CTRL, 0xF, 0xF, true);
  return v + __builtin_bit_cast(float, m);
}
__device__ __forceinline__ float row16_reduce(float v) {
  v = dpp_add<0xB1>(v);
  v = dpp_add<0x4E>(v);
  v = dpp_add<0x124>(v);
  v = dpp_add<0x128>(v);
  return v;
}

// ---------------- Kernel 0: weight precompute --------------------------
__global__ __launch_bounds__(256) void precompute_kernel(
    const float* __restrict__ Wq, const float* __restrict__ Wk,
    const float* __restrict__ bq, const float* __restrict__ bk,
    const float* __restrict__ We, const float* __restrict__ Wv,
    const float* __restrict__ bv, const float* __restrict__ Wskip,
    const float* __restrict__ bskip, const float* __restrict__ W1,
    float* __restrict__ P) {
  int t = threadIdx.x;
  for (int idx = t; idx < 1024; idx += 256) {
    int lane = idx >> 4, i = idx & 15;
    int h = lane >> 4, tt = lane & 15;
    float am = 0.f, ae = 0.f;
#pragma unroll
    for (int c = 0; c < 32; c++) {
      float wq = Wq[i * 128 + h * 32 + c];
      am += wq * Wk[tt * 128 + h * 32 + c];
      ae += wq * We[tt * 128 + h * 32 + c];
    }
    P[PMV + idx] = am * SL;
    P[MEV + idx] = ae * SL;
  }
  if (t < 64) {
    int h = t >> 4, tt = t & 15;
    float be = 0.f, up = 0.f, wp = 0.f;
#pragma unroll
    for (int c = 0; c < 32; c++) {
      be += bq[h * 32 + c] * We[tt * 128 + h * 32 + c];
      up += Wq[tt * 128 + h * 32 + c] * bk[h * 32 + c];
      wp += bq[h * 32 + c] * Wk[tt * 128 + h * 32 + c];
    }
    P[BEV + t] = be * SL;
    P[UPV + t] = up * SL;
    P[WPV + t] = wp * SL;
  }
  if (t < 4) {
    float wc = 0.f;
#pragma unroll
    for (int c = 0; c < 32; c++) wc += bq[t * 32 + c] * bk[t * 32 + c];
    P[WCV + t] = wc * SL;
  }
  // WPK4: per-lane {We[i][base], We[i][base+16], Wv[i][base], Wv[i][base+16]}
  for (int idx = t; idx < 1024; idx += 256) {
    int lane = idx >> 4, i = idx & 15;
    int h = lane >> 4, tt = lane & 15, base = h * 32 + tt;
    float4 v;
    v.x = We[i * 128 + base];
    v.y = We[i * 128 + base + 16];
    v.z = Wv[i * 128 + base];
    v.w = Wv[i * 128 + base + 16];
    ((float4*)(P + WPK4))[idx] = v;
  }
  if (t < 64) {
    int h = t >> 4, tt = t & 15, base = h * 32 + tt;
    ((float2*)(P + BVK))[t] = make_float2(bv[base], bv[base + 16]);
  }
  // WSPK: per-t16, k=0..7
  for (int idx = t; idx < 128; idx += 256) {
    int tt = idx >> 3, k = idx & 7;
    float4 v;
    v.x = Wskip[(2 * k) * 32 + tt];
    v.y = Wskip[(2 * k) * 32 + tt + 16];
    v.z = Wskip[(2 * k + 1) * 32 + tt];
    v.w = Wskip[(2 * k + 1) * 32 + tt + 16];
    ((float4*)(P + WSPK))[idx] = v;
  }
  if (t < 16)
    ((float2*)(P + BSK))[t] = make_float2(bskip[t], bskip[t + 16]);
  // W1PK: per lane, k=0..7: rows roff+(k>=4?16:0)+4*(k&3)..+3, col jj
  for (int idx = t; idx < 512; idx += 256) {
    int lane = idx >> 3, k = idx & 7;
    int jj = lane & 31;
    int r = ((lane < 32) ? 0 : 48) + ((k >= 4) ? 16 : 0) + 4 * (k & 3);
    float4 v;
    v.x = W1[(r + 0) * 32 + jj];
    v.y = W1[(r + 1) * 32 + jj];
    v.z = W1[(r + 2) * 32 + jj];
    v.w = W1[(r + 3) * 32 + jj];
    ((float4*)(P + W1PK))[idx] = v;
  }
}

// ---------------- Kernel 1: node precompute + coarse hist (fused) ------
__global__ __launch_bounds__(256) void node_linear_kernel(
    const float* __restrict__ x, const float* __restrict__ P,
    const int* __restrict__ ei, int* __restrict__ hist_all,
    float* __restrict__ y, float* __restrict__ qe,
    float* __restrict__ u4, float* __restrict__ w4) {
  __shared__ int hist[NB];
  if (blockIdx.x >= NODE_BLOCKS) {
    int b = blockIdx.x - NODE_BLOCKS;  // [0,256)
    int t = threadIdx.x;
    if (t < NB) hist[t] = 0;
    __syncthreads();
    int base = b * EPB;
    for (int i = t; i < EPB; i += 256)
      atomicAdd(&hist[ei[NE + base + i] >> 8], 1);
    __syncthreads();
    if (t < NB) hist_all[t * 256 + b] = hist[t];
    return;
  }
  int wave = threadIdx.x >> 6;
  int lane = threadIdx.x & 63;
  int n = blockIdx.x * 4 + wave;
  int h = lane >> 4, t = lane & 15;

  const float4* xp = (const float4*)(x + n * 16);
  float4 X0 = xp[0], X1 = xp[1], X2 = xp[2], X3 = xp[3];
  float xr[16] = {X0.x, X0.y, X0.z, X0.w, X1.x, X1.y, X1.z, X1.w,
                  X2.x, X2.y, X2.z, X2.w, X3.x, X3.y, X3.z, X3.w};

  const float4* pm = (const float4*)(P + PMV) + lane * 4;
  const float4* me = (const float4*)(P + MEV) + lane * 4;
  float yt = 0.f, qv = P[BEV + lane];
#pragma unroll
  for (int i4 = 0; i4 < 4; i4++) {
    float4 m = pm[i4], e = me[i4];
    yt += xr[4 * i4] * m.x + xr[4 * i4 + 1] * m.y
        + xr[4 * i4 + 2] * m.z + xr[4 * i4 + 3] * m.w;
    qv += xr[4 * i4] * e.x + xr[4 * i4 + 1] * e.y
        + xr[4 * i4 + 2] * e.z + xr[4 * i4 + 3] * e.w;
  }
  y[n * 64 + lane] = yt;
  qe[n * 64 + lane] = qv;

  float pu = P[UPV + lane] * xr[t];
  float pw = P[WPV + lane] * xr[t];
  pu = row16_reduce(pu);
  pw = row16_reduce(pw);
  if (t == 0) {
    u4[n * 4 + h] = pu;
    w4[n * 4 + h] = pw + P[WCV + h];
  }
}

// ---------------- CSR build ---------------------------------------------
__global__ __launch_bounds__(256) void scan_buckets_kernel(
    int* __restrict__ hist_all, int* __restrict__ btot) {
  int wv = blockIdx.x * 4 + (threadIdx.x >> 6);
  int l = threadIdx.x & 63;
  if (wv >= NB) return;
  int base = wv * 256;
  int run = 0;
#pragma unroll
  for (int c = 0; c < 4; c++) {
    int v = hist_all[base + c * 64 + l];
    int orig = v;
#pragma unroll
    for (int d = 1; d < 64; d <<= 1) {
      int u = __shfl_up(v, d);
      if (l >= d) v += u;
    }
    hist_all[base + c * 64 + l] = run + v - orig;
    run += __shfl(v, 63);
  }
  if (l == 0) btot[wv] = run;
}

__global__ __launch_bounds__(256) void tiny_scan_kernel(
    const int* __restrict__ btot, int* __restrict__ coarse_offs) {
  __shared__ int sc[256];
  int t = threadIdx.x;
  int v = (t < NB) ? btot[t] : 0;
  sc[t] = v;
  __syncthreads();
  for (int d = 1; d < 256; d <<= 1) {
    int u = (t >= d) ? sc[t - d] : 0;
    __syncthreads();
    sc[t] += u;
    __syncthreads();
  }
  if (t < NB) coarse_offs[t] = sc[t] - v;
  if (t == NB - 1) coarse_offs[NB] = sc[t];
}

// scatter edges into coarse-bucket order, carrying {src,eid} + ea f16
__global__ __launch_bounds__(256) void bucket_scatter_kernel(
    const int* __restrict__ ei, const float* __restrict__ edge_attr,
    const int* __restrict__ cursor_all, const int* __restrict__ coarse_offs,
    int2* __restrict__ s_tmp, uint4* __restrict__ ea_tmp) {
  __shared__ int cur[NB];
  int t = threadIdx.x, b = blockIdx.x;
  if (t < NB) cur[t] = cursor_all[t * 256 + b] + coarse_offs[t];
  __syncthreads();
  int base = b * EPB;
  for (int i = t; i < EPB; i += 256) {
    int e = base + i;
    int src = ei[e], dst = ei[NE + e];
    const float4* eap = (const float4*)(edge_attr + (size_t)e * 16);
    float4 a = eap[0], bb = eap[1], c = eap[2], d = eap[3];
    uint4 u0, u1;
    __half2 hh;
    hh = __floats2half2_rn(a.x, a.y);   u0.x = *(unsigned*)&hh;
    hh = __floats2half2_rn(a.z, a.w);   u0.y = *(unsigned*)&hh;
    hh = __floats2half2_rn(bb.x, bb.y); u0.z = *(unsigned*)&hh;
    hh = __floats2half2_rn(bb.z, bb.w); u0.w = *(unsigned*)&hh;
    hh = __floats2half2_rn(c.x, c.y);   u1.x = *(unsigned*)&hh;
    hh = __floats2half2_rn(c.z, c.w);   u1.y = *(unsigned*)&hh;
    hh = __floats2half2_rn(d.x, d.y);   u1.z = *(unsigned*)&hh;
    hh = __floats2half2_rn(d.z, d.w);   u1.w = *(unsigned*)&hh;
    int pos = atomicAdd(&cur[dst >> 8], 1);
    s_tmp[pos] = make_int2(src | ((dst & 255) << 16), e);
    ea_tmp[(size_t)pos * 2]     = u0;
    ea_tmp[(size_t)pos * 2 + 1] = u1;
  }
}

// one block per bucket -> exact CSR (offs + s_se{src,eid} + s_ea)
__global__ __launch_bounds__(256) void fine_csr_kernel(
    const int2* __restrict__ s_tmp, const uint4* __restrict__ ea_tmp,
    const int* __restrict__ coarse_offs,
    int2* __restrict__ s_se, uint4* __restrict__ s_ea4,
    int* __restrict__ offs) {
  __shared__ int cnt[256], sc[256], cur[256];
  int t = threadIdx.x, b = blockIdx.x;
  int lo = coarse_offs[b], hi = coarse_offs[b + 1];
  cnt[t] = 0;
  __syncthreads();
  for (int p = lo + t; p < hi; p += 256)
    atomicAdd(&cnt[(s_tmp[p].x >> 16) & 255], 1);
  __syncthreads();
  int myc = cnt[t];
  sc[t] = myc;
  __syncthreads();
  for (int d = 1; d < 256; d <<= 1) {
    int v = (t >= d) ? sc[t - d] : 0;
    __syncthreads();
    sc[t] += v;
    __syncthreads();
  }
  int excl = sc[t] - myc;
  cur[t] = lo + excl;
  int gd = b * 256 + t;
  if (gd <= NN) offs[gd] = lo + excl;
  __syncthreads();
  for (int p = lo + t; p < hi; p += 256) {
    int2 m = s_tmp[p];
    uint4 u0 = ea_tmp[(size_t)p * 2];
    uint4 u1 = ea_tmp[(size_t)p * 2 + 1];
    int pos = atomicAdd(&cur[(m.x >> 16) & 255], 1);
    s_se[pos] = make_int2(m.x & 0xFFFF, m.y);
    s_ea4[(size_t)pos * 2]     = u0;
    s_ea4[(size_t)pos * 2 + 1] = u1;
  }
}

// ---------------- Kernel 3: aggregation + A/C epilogue -----------------
// one wave per dst node; 16 lanes/head; sequential s_se/s_ea; 8-edge ILP;
// DPP dot reduce; packed-table epilogue (float4 weight loads).
__global__ __launch_bounds__(256) void aggregate_kernel(
    const float* __restrict__ y, const float* __restrict__ qe,
    const float* __restrict__ u4, const float* __restrict__ w4,
    const float* __restrict__ x, const __half* __restrict__ s_ea,
    const int2* __restrict__ s_se, const float* __restrict__ P,
    const float* __restrict__ b1, const int* __restrict__ offs,
    __half* __restrict__ Ah, __half* __restrict__ Cbh) {
  int wave = threadIdx.x >> 6, lane = threadIdx.x & 63;
  int n = blockIdx.x * 4 + wave;
  int h = lane >> 4, t = lane & 15;
  int gb = lane & 48;

  float yt = y[n * 64 + lane];
  float qet = qe[n * 64 + lane];
  float u_n = u4[n * 4 + h];
  int off = offs[n], end = offs[n + 1];

  float s = 0.f, ax = 0.f, ae = 0.f;
  int j = off;
  for (; j + 8 <= end; j += 8) {
    const uint4* sp = (const uint4*)&s_se[j];
    uint4 sa = sp[0], sb = sp[1], sc4 = sp[2], sd = sp[3];
    int src[8] = {(int)sa.x, (int)sa.z, (int)sb.x, (int)sb.z,
                  (int)sc4.x, (int)sc4.z, (int)sd.x, (int)sd.z};
    float xs[8], ea[8], uw[8];
#pragma unroll
    for (int u = 0; u < 8; u++) {
      xs[u] = x[(unsigned)src[u] * 16u + (unsigned)t];
      ea[u] = __half2float(s_ea[(size_t)(j + u) * 16 + t]);
      uw[u] = w4[(unsigned)src[u] * 4u + (unsigned)h];
    }
    float p[8];
#pragma unroll
    for (int u = 0; u < 8; u++) p[u] = fmaf(yt, xs[u], qet * ea[u]);
#pragma unroll
    for (int u = 0; u < 8; u++) p[u] = row16_reduce(p[u]);
#pragma unroll
    for (int u = 0; u < 8; u++) {
      float wgt = exp2f(p[u] + u_n + uw[u]);
      s += wgt;
      ax = fmaf(wgt, xs[u], ax);
      ae = fmaf(wgt, ea[u], ae);
    }
  }
  for (; j < end; j++) {
    int srcu = s_se[j].x;
    float xs = x[(unsigned)srcu * 16u + (unsigned)t];
    float ea_ = __half2float(s_ea[(size_t)j * 16 + t]);
    float uw = w4[(unsigned)srcu * 4u + (unsigned)h];
    float p = fmaf(yt, xs, qet * ea_);
    p = row16_reduce(p);
    float wgt = exp2f(p + u_n + uw);
    s += wgt;
    ax = fmaf(wgt, xs, ax);
    ae = fmaf(wgt, ea_, ae);
  }

  float inv = (end > off) ? 1.f / s : 0.f;
  float dflag = (end > off) ? 1.f : 0.f;
  float axn = ax * inv, aen = ae * inv;

  float2 bv2 = ((const float2*)(P + BVK))[lane];
  float r0 = dflag * bv2.x, r1 = dflag * bv2.y;
  const float4* wpk = (const float4*)(P + WPK4) + lane * 16;
#pragma unroll
  for (int i = 0; i < 16; i++) {
    float axi = __shfl(axn, gb | i);
    float aei = __shfl(aen, gb | i);
    float4 w = wpk[i];
    r0 += axi * w.z + aei * w.x;
    r1 += axi * w.w + aei * w.y;
  }
  // mean over heads
  r0 += __shfl_xor(r0, 16); r0 += __shfl_xor(r0, 32);
  r1 += __shfl_xor(r1, 16); r1 += __shfl_xor(r1, 32);

  // skip connection via packed Wskip
  const float4* xp4 = (const float4*)(x + n * 16);
  float4 X0 = xp4[0], X1 = xp4[1], X2 = xp4[2], X3 = xp4[3];
  float xe[8] = {X0.x, X0.y, X0.z, X0.w, X1.x, X1.y, X1.z, X1.w};
  float xo[8] = {X2.x, X2.y, X2.z, X2.w, X3.x, X3.y, X3.z, X3.w};
  float2 bs2 = ((const float2*)(P + BSK))[t];
  float sk0 = bs2.x, sk1 = bs2.y;
  const float4* wsp = (const float4*)(P + WSPK) + t * 8;
#pragma unroll
  for (int k = 0; k < 4; k++) {
    float4 w = wsp[k];
    sk0 += xe[2 * k] * w.x + xe[2 * k + 1] * w.z;
    sk1 += xe[2 * k] * w.y + xe[2 * k + 1] * w.w;
  }
#pragma unroll
  for (int k = 0; k < 4; k++) {
    float4 w = wsp[k + 4];
    sk0 += xo[2 * k] * w.x + xo[2 * k + 1] * w.z;
    sk1 += xo[2 * k] * w.y + xo[2 * k + 1] * w.w;
  }
  float o0 = 0.25f * r0 + sk0;  // out[n][t]
  float o1 = 0.25f * r1 + sk1;  // out[n][t+16]

  // A[n][jj] = out@W1[0:32]; Cb[n][jj] = out@W1[48:80] + b1  (stored f16)
  int jj = lane & 31;
  float acc = (lane < 32) ? 0.f : b1[jj];
  const float4* w1p = (const float4*)(P + W1PK) + lane * 8;
#pragma unroll
  for (int k = 0; k < 4; k++) {
    float4 w = w1p[k];
    acc += __shfl(o0, 4 * k) * w.x + __shfl(o0, 4 * k + 1) * w.y
         + __shfl(o0, 4 * k + 2) * w.z + __shfl(o0, 4 * k + 3) * w.w;
  }
#pragma unroll
  for (int k = 0; k < 4; k++) {
    float4 w = w1p[k + 4];
    acc += __shfl(o1, 4 * k) * w.x + __shfl(o1, 4 * k + 1) * w.y
         + __shfl(o1, 4 * k + 2) * w.z + __shfl(o1, 4 * k + 3) * w.w;
  }
  float nb = __shfl_xor(acc, 1);
  if ((lane & 1) == 0) {
    __half2 hh = __floats2half2_rn(acc, nb);
    if (lane < 32) *(__half2*)(Ah  + n * 32 + jj) = hh;
    else           *(__half2*)(Cbh + n * 32 + jj) = hh;
  }
}

// ---------------- Kernel 4: per-edge MLP, CSR order --------------------
__global__ __launch_bounds__(256) void mlp_kernel(
    const int2* __restrict__ s_se, const __half* __restrict__ s_ea,
    const int* __restrict__ offs,
    const __half* __restrict__ Ah, const __half* __restrict__ Cbh,
    const float* __restrict__ W1, const float* __restrict__ W2,
    const float* __restrict__ b2v, float* __restrict__ out) {
  int wave = threadIdx.x >> 6, lane = threadIdx.x & 63;
  int n = blockIdx.x * 4 + wave;
  int g = lane >> 5, l = lane & 31;

  float w1e[16];
#pragma unroll
  for (int i = 0; i < 16; i++) w1e[i] = W1[(32 + i) * 32 + l];
  float w2j = W2[l];
  float b2s = b2v[0];
  float cb = __half2float(Cbh[n * 32 + l]);
  int off = offs[n], end = offs[n + 1];

  for (int p = off + g; p < end; p += 2) {
    int2 se = s_se[p];
    float a = __half2float(Ah[(unsigned)se.x * 32u + l]);
    const uint4* eap = (const uint4*)(s_ea + (size_t)p * 16);
    uint4 u0 = eap[0], u1 = eap[1];
    float hsum = a + cb;
    const __half2* hp0 = (const __half2*)&u0;
    const __half2* hp1 = (const __half2*)&u1;
#pragma unroll
    for (int i = 0; i < 4; i++) {
      float2 f0 = __half22float2(hp0[i]);
      hsum += f0.x * w1e[2 * i] + f0.y * w1e[2 * i + 1];
      float2 f1 = __half22float2(hp1[i]);
      hsum += f1.x * w1e[8 + 2 * i] + f1.y * w1e[8 + 2 * i + 1];
    }
    float hv = fmaxf(hsum, 0.f) * w2j;
    hv += __shfl_xor(hv, 1); hv += __shfl_xor(hv, 2);
    hv += __shfl_xor(hv, 4); hv += __shfl_xor(hv, 8);
    hv += __shfl_xor(hv, 16);
    if (l == 0) out[se.y] = hv + b2s;
  }
}

// ---------------- launch -----------------------------------------------
extern "C" void kernel_launch(void* const* d_in, const int* in_sizes, int n_in,
                              void* d_out, int out_size, void* d_ws, size_t ws_size,
                              hipStream_t stream) {
  const float* x         = (const float*)d_in[0];
  const int*   ei        = (const int*)d_in[1];
  const float* edge_attr = (const float*)d_in[2];
  const float* Wq = (const float*)d_in[3],  *bq = (const float*)d_in[4];
  const float* Wk = (const float*)d_in[5],  *bk = (const float*)d_in[6];
  const float* Wv = (const float*)d_in[7],  *bv = (const float*)d_in[8];
  const float* We = (const float*)d_in[9];
  const float* Wskip = (const float*)d_in[10], *bskip = (const float*)d_in[11];
  const float* W1 = (const float*)d_in[12], *b1 = (const float*)d_in[13];
  const float* W2 = (const float*)d_in[14], *b2 = (const float*)d_in[15];
  float* out = (float*)d_out;

  // workspace layout (~91.7 MB); Ah/Cbh ALIAS ea_tmp (dead after fine_csr)
  char* w = (char*)d_ws;
  float*   y    = (float*)w;            w += (size_t)NN * 64 * 4;   // 12.8 MB
  float*   qe   = (float*)w;            w += (size_t)NN * 64 * 4;   // 12.8 MB
  float*   u4   = (float*)w;            w += (size_t)NN * 4 * 4;    // 0.8 MB
  float*   w4   = (float*)w;            w += (size_t)NN * 4 * 4;    // 0.8 MB
  int2*    s_se = (int2*)w;             w += (size_t)NE * 8;        // 6.4 MB
  int2*    s_tmp = (int2*)w;            w += (size_t)NE * 8;        // 6.4 MB
  uint4*   s_ea4 = (uint4*)w;           w += (size_t)NE * 32;       // 25.6 MB
  uint4*   ea_tmp = (uint4*)w;          // 25.6 MB (Ah, Cbh alias inside)
  __half*  Ah   = (__half*)ea_tmp;                          // 3.2 MB
  __half*  Cbh  = (__half*)((char*)ea_tmp + (size_t)NN * 32 * 2); // 3.2 MB
  w += (size_t)NE * 32;
  int*     hist_all = (int*)w;          w += (size_t)256 * 256 * 4; // 256 KB
  int*     btot = (int*)w;              w += 256 * 4;
  int*     coarse_offs = (int*)w;       w += 256 * 4;
  int*     offs = (int*)w;              w += ((size_t)NN + 1) * 4;
  float*   P    = (float*)w;            w += (size_t)P_TOTAL * 4;

  precompute_kernel<<<1, 256, 0, stream>>>(Wq, Wk, bq, bk, We, Wv, bv,
                                           Wskip, bskip, W1, P);
  node_linear_kernel<<<NODE_BLOCKS + 256, 256, 0, stream>>>(
      x, P, ei, hist_all, y, qe, u4, w4);
  scan_buckets_kernel<<<49, 256, 0, stream>>>(hist_all, btot);
  tiny_scan_kernel<<<1, 256, 0, stream>>>(btot, coarse_offs);
  bucket_scatter_kernel<<<256, 256, 0, stream>>>(ei, edge_attr, hist_all,
                                                 coarse_offs, s_tmp, ea_tmp);
  fine_csr_kernel<<<NB, 256, 0, stream>>>(s_tmp, ea_tmp, coarse_offs,
                                          s_se, s_ea4, offs);
  aggregate_kernel<<<NN / 4, 256, 0, stream>>>(y, qe, u4, w4, x,
                                               (const __half*)s_ea4, s_se,
                                               P, b1, offs, Ah, Cbh);
  mlp_kernel<<<NN / 4, 256, 0, stream>>>(s_se, (const __half*)s_ea4, offs,
                                         Ah, Cbh, W1, W2, b2, out);
}

// Round 15
// 265.260 us; speedup vs baseline: 1.4661x; 1.4661x over previous
//
#include <hip/hip_runtime.h>
#include <hip/hip_fp16.h>

#define NN 50000
#define NE 800000
// IN_C=16, EDGE_IN=16, HID=32, HEADS=4, HC=128
#define NB 196            // coarse buckets = ceil(NN/256)
#define EPB 3125          // edges per bucket-build block (NE/256)
#define NODE_BLOCKS 12500 // NN/4

// scale folded into all alpha components: log2(e)/sqrt(32)
#define SL 0.25506413f

// packed table offsets (floats)
#define PMV 0       // 1024: y table, lane-major [lane][i]
#define MEV 1024    // 1024: qe table
#define BEV 2048    // 64
#define UPV 2112    // 64
#define WPV 2176    // 64
#define WCV 2240    // 4
// vector tables, ALL [i][lane] layout (lane stride 16B -> coalesced):
#define WPK4 2304   // 4096: [i][lane] {We_lo,We_hi,Wv_lo,Wv_hi} (float4)
#define BVK  6400   // 128: [lane] {bv_lo, bv_hi} (float2)
#define WSPK 6528   // 512: [k][t16] {Wskip[2k][t],Wskip[2k][t+16],Wskip[2k+1][t],Wskip[2k+1][t+16]} (float4)
#define BSK  7040   // 32: [t] {bskip[t], bskip[t+16]} (float2)
#define W1PK 7072   // 2048: [k][lane] W1 A/C column chunks (float4)
#define P_TOTAL 9120

// DPP-based add over lanes: quad xor1=0xB1, xor2=0x4E, row_ror:4=0x124,
// row_ror:8=0x128 (rows are 16 lanes = one head group). VALU-pipe only.
template <int CTRL>
__device__ __forceinline__ float dpp_add(float v) {
  int m = __builtin_amdgcn_update_dpp(0, __builtin_bit_cast(int, v), CTRL, 0xF, 0xF, true);
  return v + __builtin_bit_cast(float, m);
}
__device__ __forceinline__ float row16_reduce(float v) {
  v = dpp_add<0xB1>(v);
  v = dpp_add<0x4E>(v);
  v = dpp_add<0x124>(v);
  v = dpp_add<0x128>(v);
  return v;
}

// ---------------- Kernel 0: weight precompute --------------------------
__global__ __launch_bounds__(256) void precompute_kernel(
    const float* __restrict__ Wq, const float* __restrict__ Wk,
    const float* __restrict__ bq, const float* __restrict__ bk,
    const float* __restrict__ We, const float* __restrict__ Wv,
    const float* __restrict__ bv, const float* __restrict__ Wskip,
    const float* __restrict__ bskip, const float* __restrict__ W1,
    float* __restrict__ P) {
  int t = threadIdx.x;
  for (int idx = t; idx < 1024; idx += 256) {
    int lane = idx >> 4, i = idx & 15;
    int h = lane >> 4, tt = lane & 15;
    float am = 0.f, ae = 0.f;
#pragma unroll
    for (int c = 0; c < 32; c++) {
      float wq = Wq[i * 128 + h * 32 + c];
      am += wq * Wk[tt * 128 + h * 32 + c];
      ae += wq * We[tt * 128 + h * 32 + c];
    }
    P[PMV + idx] = am * SL;
    P[MEV + idx] = ae * SL;
  }
  if (t < 64) {
    int h = t >> 4, tt = t & 15;
    float be = 0.f, up = 0.f, wp = 0.f;
#pragma unroll
    for (int c = 0; c < 32; c++) {
      be += bq[h * 32 + c] * We[tt * 128 + h * 32 + c];
      up += Wq[tt * 128 + h * 32 + c] * bk[h * 32 + c];
      wp += bq[h * 32 + c] * Wk[tt * 128 + h * 32 + c];
    }
    P[BEV + t] = be * SL;
    P[UPV + t] = up * SL;
    P[WPV + t] = wp * SL;
  }
  if (t < 4) {
    float wc = 0.f;
#pragma unroll
    for (int c = 0; c < 32; c++) wc += bq[t * 32 + c] * bk[t * 32 + c];
    P[WCV + t] = wc * SL;
  }
  // WPK4 [i][lane]: {We[i][base], We[i][base+16], Wv[i][base], Wv[i][base+16]}
  for (int idx = t; idx < 1024; idx += 256) {
    int i = idx >> 6, lane = idx & 63;
    int h = lane >> 4, tt = lane & 15, base = h * 32 + tt;
    float4 v;
    v.x = We[i * 128 + base];
    v.y = We[i * 128 + base + 16];
    v.z = Wv[i * 128 + base];
    v.w = Wv[i * 128 + base + 16];
    ((float4*)(P + WPK4))[i * 64 + lane] = v;
  }
  if (t < 64) {
    int h = t >> 4, tt = t & 15, base = h * 32 + tt;
    ((float2*)(P + BVK))[t] = make_float2(bv[base], bv[base + 16]);
  }
  // WSPK [k][t16]
  for (int idx = t; idx < 128; idx += 256) {
    int k = idx >> 4, tt = idx & 15;
    float4 v;
    v.x = Wskip[(2 * k) * 32 + tt];
    v.y = Wskip[(2 * k) * 32 + tt + 16];
    v.z = Wskip[(2 * k + 1) * 32 + tt];
    v.w = Wskip[(2 * k + 1) * 32 + tt + 16];
    ((float4*)(P + WSPK))[k * 16 + tt] = v;
  }
  if (t < 16)
    ((float2*)(P + BSK))[t] = make_float2(bskip[t], bskip[t + 16]);
  // W1PK [k][lane]: rows roff+(k>=4?16:0)+4*(k&3)..+3, col jj
  for (int idx = t; idx < 512; idx += 256) {
    int k = idx >> 6, lane = idx & 63;
    int jj = lane & 31;
    int r = ((lane < 32) ? 0 : 48) + ((k >= 4) ? 16 : 0) + 4 * (k & 3);
    float4 v;
    v.x = W1[(r + 0) * 32 + jj];
    v.y = W1[(r + 1) * 32 + jj];
    v.z = W1[(r + 2) * 32 + jj];
    v.w = W1[(r + 3) * 32 + jj];
    ((float4*)(P + W1PK))[k * 64 + lane] = v;
  }
}

// ---------------- Kernel 1: node precompute + coarse hist (fused) ------
__global__ __launch_bounds__(256) void node_linear_kernel(
    const float* __restrict__ x, const float* __restrict__ P,
    const int* __restrict__ ei, int* __restrict__ hist_all,
    float* __restrict__ y, float* __restrict__ qe,
    float* __restrict__ u4, float* __restrict__ w4) {
  __shared__ int hist[NB];
  if (blockIdx.x >= NODE_BLOCKS) {
    int b = blockIdx.x - NODE_BLOCKS;  // [0,256)
    int t = threadIdx.x;
    if (t < NB) hist[t] = 0;
    __syncthreads();
    int base = b * EPB;
    for (int i = t; i < EPB; i += 256)
      atomicAdd(&hist[ei[NE + base + i] >> 8], 1);
    __syncthreads();
    if (t < NB) hist_all[t * 256 + b] = hist[t];
    return;
  }
  int wave = threadIdx.x >> 6;
  int lane = threadIdx.x & 63;
  int n = blockIdx.x * 4 + wave;
  int h = lane >> 4, t = lane & 15;

  const float4* xp = (const float4*)(x + n * 16);
  float4 X0 = xp[0], X1 = xp[1], X2 = xp[2], X3 = xp[3];
  float xr[16] = {X0.x, X0.y, X0.z, X0.w, X1.x, X1.y, X1.z, X1.w,
                  X2.x, X2.y, X2.z, X2.w, X3.x, X3.y, X3.z, X3.w};

  const float4* pm = (const float4*)(P + PMV) + lane * 4;
  const float4* me = (const float4*)(P + MEV) + lane * 4;
  float yt = 0.f, qv = P[BEV + lane];
#pragma unroll
  for (int i4 = 0; i4 < 4; i4++) {
    float4 m = pm[i4], e = me[i4];
    yt += xr[4 * i4] * m.x + xr[4 * i4 + 1] * m.y
        + xr[4 * i4 + 2] * m.z + xr[4 * i4 + 3] * m.w;
    qv += xr[4 * i4] * e.x + xr[4 * i4 + 1] * e.y
        + xr[4 * i4 + 2] * e.z + xr[4 * i4 + 3] * e.w;
  }
  y[n * 64 + lane] = yt;
  qe[n * 64 + lane] = qv;

  float pu = P[UPV + lane] * xr[t];
  float pw = P[WPV + lane] * xr[t];
  pu = row16_reduce(pu);
  pw = row16_reduce(pw);
  if (t == 0) {
    u4[n * 4 + h] = pu;
    w4[n * 4 + h] = pw + P[WCV + h];
  }
}

// ---------------- CSR build ---------------------------------------------
__global__ __launch_bounds__(256) void scan_buckets_kernel(
    int* __restrict__ hist_all, int* __restrict__ btot) {
  int wv = blockIdx.x * 4 + (threadIdx.x >> 6);
  int l = threadIdx.x & 63;
  if (wv >= NB) return;
  int base = wv * 256;
  int run = 0;
#pragma unroll
  for (int c = 0; c < 4; c++) {
    int v = hist_all[base + c * 64 + l];
    int orig = v;
#pragma unroll
    for (int d = 1; d < 64; d <<= 1) {
      int u = __shfl_up(v, d);
      if (l >= d) v += u;
    }
    hist_all[base + c * 64 + l] = run + v - orig;
    run += __shfl(v, 63);
  }
  if (l == 0) btot[wv] = run;
}

__global__ __launch_bounds__(256) void tiny_scan_kernel(
    const int* __restrict__ btot, int* __restrict__ coarse_offs) {
  __shared__ int sc[256];
  int t = threadIdx.x;
  int v = (t < NB) ? btot[t] : 0;
  sc[t] = v;
  __syncthreads();
  for (int d = 1; d < 256; d <<= 1) {
    int u = (t >= d) ? sc[t - d] : 0;
    __syncthreads();
    sc[t] += u;
    __syncthreads();
  }
  if (t < NB) coarse_offs[t] = sc[t] - v;
  if (t == NB - 1) coarse_offs[NB] = sc[t];
}

// scatter edges into coarse-bucket order, carrying {src,eid} + ea f16
__global__ __launch_bounds__(256) void bucket_scatter_kernel(
    const int* __restrict__ ei, const float* __restrict__ edge_attr,
    const int* __restrict__ cursor_all, const int* __restrict__ coarse_offs,
    int2* __restrict__ s_tmp, uint4* __restrict__ ea_tmp) {
  __shared__ int cur[NB];
  int t = threadIdx.x, b = blockIdx.x;
  if (t < NB) cur[t] = cursor_all[t * 256 + b] + coarse_offs[t];
  __syncthreads();
  int base = b * EPB;
  for (int i = t; i < EPB; i += 256) {
    int e = base + i;
    int src = ei[e], dst = ei[NE + e];
    const float4* eap = (const float4*)(edge_attr + (size_t)e * 16);
    float4 a = eap[0], bb = eap[1], c = eap[2], d = eap[3];
    uint4 u0, u1;
    __half2 hh;
    hh = __floats2half2_rn(a.x, a.y);   u0.x = *(unsigned*)&hh;
    hh = __floats2half2_rn(a.z, a.w);   u0.y = *(unsigned*)&hh;
    hh = __floats2half2_rn(bb.x, bb.y); u0.z = *(unsigned*)&hh;
    hh = __floats2half2_rn(bb.z, bb.w); u0.w = *(unsigned*)&hh;
    hh = __floats2half2_rn(c.x, c.y);   u1.x = *(unsigned*)&hh;
    hh = __floats2half2_rn(c.z, c.w);   u1.y = *(unsigned*)&hh;
    hh = __floats2half2_rn(d.x, d.y);   u1.z = *(unsigned*)&hh;
    hh = __floats2half2_rn(d.z, d.w);   u1.w = *(unsigned*)&hh;
    int pos = atomicAdd(&cur[dst >> 8], 1);
    s_tmp[pos] = make_int2(src | ((dst & 255) << 16), e);
    ea_tmp[(size_t)pos * 2]     = u0;
    ea_tmp[(size_t)pos * 2 + 1] = u1;
  }
}

// one block per bucket -> exact CSR (offs + s_se{src,eid} + s_ea)
__global__ __launch_bounds__(256) void fine_csr_kernel(
    const int2* __restrict__ s_tmp, const uint4* __restrict__ ea_tmp,
    const int* __restrict__ coarse_offs,
    int2* __restrict__ s_se, uint4* __restrict__ s_ea4,
    int* __restrict__ offs) {
  __shared__ int cnt[256], sc[256], cur[256];
  int t = threadIdx.x, b = blockIdx.x;
  int lo = coarse_offs[b], hi = coarse_offs[b + 1];
  cnt[t] = 0;
  __syncthreads();
  for (int p = lo + t; p < hi; p += 256)
    atomicAdd(&cnt[(s_tmp[p].x >> 16) & 255], 1);
  __syncthreads();
  int myc = cnt[t];
  sc[t] = myc;
  __syncthreads();
  for (int d = 1; d < 256; d <<= 1) {
    int v = (t >= d) ? sc[t - d] : 0;
    __syncthreads();
    sc[t] += v;
    __syncthreads();
  }
  int excl = sc[t] - myc;
  cur[t] = lo + excl;
  int gd = b * 256 + t;
  if (gd <= NN) offs[gd] = lo + excl;
  __syncthreads();
  for (int p = lo + t; p < hi; p += 256) {
    int2 m = s_tmp[p];
    uint4 u0 = ea_tmp[(size_t)p * 2];
    uint4 u1 = ea_tmp[(size_t)p * 2 + 1];
    int pos = atomicAdd(&cur[(m.x >> 16) & 255], 1);
    s_se[pos] = make_int2(m.x & 0xFFFF, m.y);
    s_ea4[(size_t)pos * 2]     = u0;
    s_ea4[(size_t)pos * 2 + 1] = u1;
  }
}

// ---------------- Kernel 3: aggregation + A/C epilogue -----------------
// one wave per dst node; 16 lanes/head; sequential s_se/s_ea; 8-edge ILP;
// DPP dot reduce; [i][lane]-packed epilogue (coalesced float4 loads).
__global__ __launch_bounds__(256) void aggregate_kernel(
    const float* __restrict__ y, const float* __restrict__ qe,
    const float* __restrict__ u4, const float* __restrict__ w4,
    const float* __restrict__ x, const __half* __restrict__ s_ea,
    const int2* __restrict__ s_se, const float* __restrict__ P,
    const float* __restrict__ b1, const int* __restrict__ offs,
    __half* __restrict__ Ah, __half* __restrict__ Cbh) {
  int wave = threadIdx.x >> 6, lane = threadIdx.x & 63;
  int n = blockIdx.x * 4 + wave;
  int h = lane >> 4, t = lane & 15;
  int gb = lane & 48;

  float yt = y[n * 64 + lane];
  float qet = qe[n * 64 + lane];
  float u_n = u4[n * 4 + h];
  int off = offs[n], end = offs[n + 1];

  float s = 0.f, ax = 0.f, ae = 0.f;
  int j = off;
  for (; j + 8 <= end; j += 8) {
    const uint4* sp = (const uint4*)&s_se[j];
    uint4 sa = sp[0], sb = sp[1], sc4 = sp[2], sd = sp[3];
    int src[8] = {(int)sa.x, (int)sa.z, (int)sb.x, (int)sb.z,
                  (int)sc4.x, (int)sc4.z, (int)sd.x, (int)sd.z};
    float xs[8], ea[8], uw[8];
#pragma unroll
    for (int u = 0; u < 8; u++) {
      xs[u] = x[(unsigned)src[u] * 16u + (unsigned)t];
      ea[u] = __half2float(s_ea[(size_t)(j + u) * 16 + t]);
      uw[u] = w4[(unsigned)src[u] * 4u + (unsigned)h];
    }
    float p[8];
#pragma unroll
    for (int u = 0; u < 8; u++) p[u] = fmaf(yt, xs[u], qet * ea[u]);
#pragma unroll
    for (int u = 0; u < 8; u++) p[u] = row16_reduce(p[u]);
#pragma unroll
    for (int u = 0; u < 8; u++) {
      float wgt = exp2f(p[u] + u_n + uw[u]);
      s += wgt;
      ax = fmaf(wgt, xs[u], ax);
      ae = fmaf(wgt, ea[u], ae);
    }
  }
  for (; j < end; j++) {
    int srcu = s_se[j].x;
    float xs = x[(unsigned)srcu * 16u + (unsigned)t];
    float ea_ = __half2float(s_ea[(size_t)j * 16 + t]);
    float uw = w4[(unsigned)srcu * 4u + (unsigned)h];
    float p = fmaf(yt, xs, qet * ea_);
    p = row16_reduce(p);
    float wgt = exp2f(p + u_n + uw);
    s += wgt;
    ax = fmaf(wgt, xs, ax);
    ae = fmaf(wgt, ea_, ae);
  }

  float inv = (end > off) ? 1.f / s : 0.f;
  float dflag = (end > off) ? 1.f : 0.f;
  float axn = ax * inv, aen = ae * inv;

  float2 bv2 = ((const float2*)(P + BVK))[lane];
  float r0 = dflag * bv2.x, r1 = dflag * bv2.y;
  const float4* wpk = (const float4*)(P + WPK4);
#pragma unroll
  for (int i = 0; i < 16; i++) {
    float axi = __shfl(axn, gb | i);
    float aei = __shfl(aen, gb | i);
    float4 w = wpk[i * 64 + lane];
    r0 += axi * w.z + aei * w.x;
    r1 += axi * w.w + aei * w.y;
  }
  // mean over heads
  r0 += __shfl_xor(r0, 16); r0 += __shfl_xor(r0, 32);
  r1 += __shfl_xor(r1, 16); r1 += __shfl_xor(r1, 32);

  // skip connection via packed Wskip [k][t16]
  const float4* xp4 = (const float4*)(x + n * 16);
  float4 X0 = xp4[0], X1 = xp4[1], X2 = xp4[2], X3 = xp4[3];
  float xe[8] = {X0.x, X0.y, X0.z, X0.w, X1.x, X1.y, X1.z, X1.w};
  float xo[8] = {X2.x, X2.y, X2.z, X2.w, X3.x, X3.y, X3.z, X3.w};
  float2 bs2 = ((const float2*)(P + BSK))[t];
  float sk0 = bs2.x, sk1 = bs2.y;
  const float4* wsp = (const float4*)(P + WSPK);
#pragma unroll
  for (int k = 0; k < 4; k++) {
    float4 w = wsp[k * 16 + t];
    sk0 += xe[2 * k] * w.x + xe[2 * k + 1] * w.z;
    sk1 += xe[2 * k] * w.y + xe[2 * k + 1] * w.w;
  }
#pragma unroll
  for (int k = 0; k < 4; k++) {
    float4 w = wsp[(k + 4) * 16 + t];
    sk0 += xo[2 * k] * w.x + xo[2 * k + 1] * w.z;
    sk1 += xo[2 * k] * w.y + xo[2 * k + 1] * w.w;
  }
  float o0 = 0.25f * r0 + sk0;  // out[n][t]
  float o1 = 0.25f * r1 + sk1;  // out[n][t+16]

  // A[n][jj] = out@W1[0:32]; Cb[n][jj] = out@W1[48:80] + b1  (stored f16)
  int jj = lane & 31;
  float acc = (lane < 32) ? 0.f : b1[jj];
  const float4* w1p = (const float4*)(P + W1PK);
#pragma unroll
  for (int k = 0; k < 4; k++) {
    float4 w = w1p[k * 64 + lane];
    acc += __shfl(o0, 4 * k) * w.x + __shfl(o0, 4 * k + 1) * w.y
         + __shfl(o0, 4 * k + 2) * w.z + __shfl(o0, 4 * k + 3) * w.w;
  }
#pragma unroll
  for (int k = 0; k < 4; k++) {
    float4 w = w1p[(k + 4) * 64 + lane];
    acc += __shfl(o1, 4 * k) * w.x + __shfl(o1, 4 * k + 1) * w.y
         + __shfl(o1, 4 * k + 2) * w.z + __shfl(o1, 4 * k + 3) * w.w;
  }
  float nb = __shfl_xor(acc, 1);
  if ((lane & 1) == 0) {
    __half2 hh = __floats2half2_rn(acc, nb);
    if (lane < 32) *(__half2*)(Ah  + n * 32 + jj) = hh;
    else           *(__half2*)(Cbh + n * 32 + jj) = hh;
  }
}

// ---------------- Kernel 4: per-edge MLP, CSR order --------------------
__global__ __launch_bounds__(256) void mlp_kernel(
    const int2* __restrict__ s_se, const __half* __restrict__ s_ea,
    const int* __restrict__ offs,
    const __half* __restrict__ Ah, const __half* __restrict__ Cbh,
    const float* __restrict__ W1, const float* __restrict__ W2,
    const float* __restrict__ b2v, float* __restrict__ out) {
  int wave = threadIdx.x >> 6, lane = threadIdx.x & 63;
  int n = blockIdx.x * 4 + wave;
  int g = lane >> 5, l = lane & 31;

  float w1e[16];
#pragma unroll
  for (int i = 0; i < 16; i++) w1e[i] = W1[(32 + i) * 32 + l];
  float w2j = W2[l];
  float b2s = b2v[0];
  float cb = __half2float(Cbh[n * 32 + l]);
  int off = offs[n], end = offs[n + 1];

  for (int p = off + g; p < end; p += 2) {
    int2 se = s_se[p];
    float a = __half2float(Ah[(unsigned)se.x * 32u + l]);
    const uint4* eap = (const uint4*)(s_ea + (size_t)p * 16);
    uint4 u0 = eap[0], u1 = eap[1];
    float hsum = a + cb;
    const __half2* hp0 = (const __half2*)&u0;
    const __half2* hp1 = (const __half2*)&u1;
#pragma unroll
    for (int i = 0; i < 4; i++) {
      float2 f0 = __half22float2(hp0[i]);
      hsum += f0.x * w1e[2 * i] + f0.y * w1e[2 * i + 1];
      float2 f1 = __half22float2(hp1[i]);
      hsum += f1.x * w1e[8 + 2 * i] + f1.y * w1e[8 + 2 * i + 1];
    }
    float hv = fmaxf(hsum, 0.f) * w2j;
    hv += __shfl_xor(hv, 1); hv += __shfl_xor(hv, 2);
    hv += __shfl_xor(hv, 4); hv += __shfl_xor(hv, 8);
    hv += __shfl_xor(hv, 16);
    if (l == 0) out[se.y] = hv + b2s;
  }
}

// ---------------- launch -----------------------------------------------
extern "C" void kernel_launch(void* const* d_in, const int* in_sizes, int n_in,
                              void* d_out, int out_size, void* d_ws, size_t ws_size,
                              hipStream_t stream) {
  const float* x         = (const float*)d_in[0];
  const int*   ei        = (const int*)d_in[1];
  const float* edge_attr = (const float*)d_in[2];
  const float* Wq = (const float*)d_in[3],  *bq = (const float*)d_in[4];
  const float* Wk = (const float*)d_in[5],  *bk = (const float*)d_in[6];
  const float* Wv = (const float*)d_in[7],  *bv = (const float*)d_in[8];
  const float* We = (const float*)d_in[9];
  const float* Wskip = (const float*)d_in[10], *bskip = (const float*)d_in[11];
  const float* W1 = (const float*)d_in[12], *b1 = (const float*)d_in[13];
  const float* W2 = (const float*)d_in[14], *b2 = (const float*)d_in[15];
  float* out = (float*)d_out;

  // workspace layout (~91.7 MB); Ah/Cbh ALIAS ea_tmp (dead after fine_csr)
  char* w = (char*)d_ws;
  float*   y    = (float*)w;            w += (size_t)NN * 64 * 4;   // 12.8 MB
  float*   qe   = (float*)w;            w += (size_t)NN * 64 * 4;   // 12.8 MB
  float*   u4   = (float*)w;            w += (size_t)NN * 4 * 4;    // 0.8 MB
  float*   w4   = (float*)w;            w += (size_t)NN * 4 * 4;    // 0.8 MB
  int2*    s_se = (int2*)w;             w += (size_t)NE * 8;        // 6.4 MB
  int2*    s_tmp = (int2*)w;            w += (size_t)NE * 8;        // 6.4 MB
  uint4*   s_ea4 = (uint4*)w;           w += (size_t)NE * 32;       // 25.6 MB
  uint4*   ea_tmp = (uint4*)w;          // 25.6 MB (Ah, Cbh alias inside)
  __half*  Ah   = (__half*)ea_tmp;                          // 3.2 MB
  __half*  Cbh  = (__half*)((char*)ea_tmp + (size_t)NN * 32 * 2); // 3.2 MB
  w += (size_t)NE * 32;
  int*     hist_all = (int*)w;          w += (size_t)256 * 256 * 4; // 256 KB
  int*     btot = (int*)w;              w += 256 * 4;
  int*     coarse_offs = (int*)w;       w += 256 * 4;
  int*     offs = (int*)w;              w += ((size_t)NN + 1) * 4;
  float*   P    = (float*)w;            w += (size_t)P_TOTAL * 4;

  precompute_kernel<<<1, 256, 0, stream>>>(Wq, Wk, bq, bk, We, Wv, bv,
                                           Wskip, bskip, W1, P);
  node_linear_kernel<<<NODE_BLOCKS + 256, 256, 0, stream>>>(
      x, P, ei, hist_all, y, qe, u4, w4);
  scan_buckets_kernel<<<49, 256, 0, stream>>>(hist_all, btot);
  tiny_scan_kernel<<<1, 256, 0, stream>>>(btot, coarse_offs);
  bucket_scatter_kernel<<<256, 256, 0, stream>>>(ei, edge_attr, hist_all,
                                                 coarse_offs, s_tmp, ea_tmp);
  fine_csr_kernel<<<NB, 256, 0, stream>>>(s_tmp, ea_tmp, coarse_offs,
                                          s_se, s_ea4, offs);
  aggregate_kernel<<<NN / 4, 256, 0, stream>>>(y, qe, u4, w4, x,
                                               (const __half*)s_ea4, s_se,
                                               P, b1, offs, Ah, Cbh);
  mlp_kernel<<<NN / 4, 256, 0, stream>>>(s_se, (const __half*)s_ea4, offs,
                                         Ah, Cbh, W1, W2, b2, out);
}

// Round 16
// 253.910 us; speedup vs baseline: 1.5317x; 1.0447x over previous
//
#include <hip/hip_runtime.h>
#include <hip/hip_fp16.h>

#define NN 50000
#define NE 800000
// IN_C=16, EDGE_IN=16, HID=32, HEADS=4, HC=128
#define NB 196            // coarse buckets = ceil(NN/256)
#define EPB 3125          // edges per bucket-build block (NE/256)
#define NODE_BLOCKS 12500 // NN/4

// scale folded into all alpha components: log2(e)/sqrt(32)
#define SL 0.25506413f

// packed table offsets (floats): PMV/MEV lane-major [lane][i] (per-lane
// float4 reads, L1-broadcast across waves), BEV/UPV/WPV per-lane scalars
#define PMV 0
#define MEV 1024
#define BEV 2048
#define UPV 2112
#define WPV 2176
#define WCV 2240
#define P_TOTAL 2304

// DPP-based add over lanes: quad xor1=0xB1, xor2=0x4E, row_ror:4=0x124,
// row_ror:8=0x128 (rows are 16 lanes = one head group). VALU-pipe only.
template <int CTRL>
__device__ __forceinline__ float dpp_add(float v) {
  int m = __builtin_amdgcn_update_dpp(0, __builtin_bit_cast(int, v), CTRL, 0xF, 0xF, true);
  return v + __builtin_bit_cast(float, m);
}
__device__ __forceinline__ float row16_reduce(float v) {
  v = dpp_add<0xB1>(v);
  v = dpp_add<0x4E>(v);
  v = dpp_add<0x124>(v);
  v = dpp_add<0x128>(v);
  return v;
}

// ---------------- Kernel 0: weight precompute --------------------------
__global__ __launch_bounds__(256) void precompute_kernel(
    const float* __restrict__ Wq, const float* __restrict__ Wk,
    const float* __restrict__ bq, const float* __restrict__ bk,
    const float* __restrict__ We, float* __restrict__ P) {
  int t = threadIdx.x;
  for (int idx = t; idx < 1024; idx += 256) {
    int lane = idx >> 4, i = idx & 15;
    int h = lane >> 4, tt = lane & 15;
    float am = 0.f, ae = 0.f;
#pragma unroll
    for (int c = 0; c < 32; c++) {
      float wq = Wq[i * 128 + h * 32 + c];
      am += wq * Wk[tt * 128 + h * 32 + c];
      ae += wq * We[tt * 128 + h * 32 + c];
    }
    P[PMV + idx] = am * SL;
    P[MEV + idx] = ae * SL;
  }
  if (t < 64) {
    int h = t >> 4, tt = t & 15;
    float be = 0.f, up = 0.f, wp = 0.f;
#pragma unroll
    for (int c = 0; c < 32; c++) {
      be += bq[h * 32 + c] * We[tt * 128 + h * 32 + c];
      up += Wq[tt * 128 + h * 32 + c] * bk[h * 32 + c];
      wp += bq[h * 32 + c] * Wk[tt * 128 + h * 32 + c];
    }
    P[BEV + t] = be * SL;
    P[UPV + t] = up * SL;
    P[WPV + t] = wp * SL;
  }
  if (t < 4) {
    float wc = 0.f;
#pragma unroll
    for (int c = 0; c < 32; c++) wc += bq[t * 32 + c] * bk[t * 32 + c];
    P[WCV + t] = wc * SL;
  }
}

// ---------------- Kernel 1: node precompute + coarse hist (fused) ------
__global__ __launch_bounds__(256) void node_linear_kernel(
    const float* __restrict__ x, const float* __restrict__ P,
    const int* __restrict__ ei, int* __restrict__ hist_all,
    float* __restrict__ y, float* __restrict__ qe,
    float* __restrict__ u4, float* __restrict__ w4) {
  __shared__ int hist[NB];
  if (blockIdx.x >= NODE_BLOCKS) {
    int b = blockIdx.x - NODE_BLOCKS;  // [0,256)
    int t = threadIdx.x;
    if (t < NB) hist[t] = 0;
    __syncthreads();
    int base = b * EPB;
    for (int i = t; i < EPB; i += 256)
      atomicAdd(&hist[ei[NE + base + i] >> 8], 1);
    __syncthreads();
    if (t < NB) hist_all[t * 256 + b] = hist[t];
    return;
  }
  int wave = threadIdx.x >> 6;
  int lane = threadIdx.x & 63;
  int n = blockIdx.x * 4 + wave;
  int h = lane >> 4, t = lane & 15;

  const float4* xp = (const float4*)(x + n * 16);
  float4 X0 = xp[0], X1 = xp[1], X2 = xp[2], X3 = xp[3];
  float xr[16] = {X0.x, X0.y, X0.z, X0.w, X1.x, X1.y, X1.z, X1.w,
                  X2.x, X2.y, X2.z, X2.w, X3.x, X3.y, X3.z, X3.w};

  const float4* pm = (const float4*)(P + PMV) + lane * 4;
  const float4* me = (const float4*)(P + MEV) + lane * 4;
  float yt = 0.f, qv = P[BEV + lane];
#pragma unroll
  for (int i4 = 0; i4 < 4; i4++) {
    float4 m = pm[i4], e = me[i4];
    yt += xr[4 * i4] * m.x + xr[4 * i4 + 1] * m.y
        + xr[4 * i4 + 2] * m.z + xr[4 * i4 + 3] * m.w;
    qv += xr[4 * i4] * e.x + xr[4 * i4 + 1] * e.y
        + xr[4 * i4 + 2] * e.z + xr[4 * i4 + 3] * e.w;
  }
  y[n * 64 + lane] = yt;
  qe[n * 64 + lane] = qv;

  float pu = P[UPV + lane] * xr[t];
  float pw = P[WPV + lane] * xr[t];
  pu = row16_reduce(pu);
  pw = row16_reduce(pw);
  if (t == 0) {
    u4[n * 4 + h] = pu;
    w4[n * 4 + h] = pw + P[WCV + h];
  }
}

// ---------------- CSR build ---------------------------------------------
__global__ __launch_bounds__(256) void scan_buckets_kernel(
    int* __restrict__ hist_all, int* __restrict__ btot) {
  int wv = blockIdx.x * 4 + (threadIdx.x >> 6);
  int l = threadIdx.x & 63;
  if (wv >= NB) return;
  int base = wv * 256;
  int run = 0;
#pragma unroll
  for (int c = 0; c < 4; c++) {
    int v = hist_all[base + c * 64 + l];
    int orig = v;
#pragma unroll
    for (int d = 1; d < 64; d <<= 1) {
      int u = __shfl_up(v, d);
      if (l >= d) v += u;
    }
    hist_all[base + c * 64 + l] = run + v - orig;
    run += __shfl(v, 63);
  }
  if (l == 0) btot[wv] = run;
}

__global__ __launch_bounds__(256) void tiny_scan_kernel(
    const int* __restrict__ btot, int* __restrict__ coarse_offs) {
  __shared__ int sc[256];
  int t = threadIdx.x;
  int v = (t < NB) ? btot[t] : 0;
  sc[t] = v;
  __syncthreads();
  for (int d = 1; d < 256; d <<= 1) {
    int u = (t >= d) ? sc[t - d] : 0;
    __syncthreads();
    sc[t] += u;
    __syncthreads();
  }
  if (t < NB) coarse_offs[t] = sc[t] - v;
  if (t == NB - 1) coarse_offs[NB] = sc[t];
}

// scatter edge META only (8B) into coarse-bucket order
__global__ __launch_bounds__(256) void bucket_scatter_kernel(
    const int* __restrict__ ei, const int* __restrict__ cursor_all,
    const int* __restrict__ coarse_offs, int2* __restrict__ s_tmp) {
  __shared__ int cur[NB];
  int t = threadIdx.x, b = blockIdx.x;
  if (t < NB) cur[t] = cursor_all[t * 256 + b] + coarse_offs[t];
  __syncthreads();
  int base = b * EPB;
  for (int i = t; i < EPB; i += 256) {
    int e = base + i;
    int src = ei[e], dst = ei[NE + e];
    int pos = atomicAdd(&cur[dst >> 8], 1);
    s_tmp[pos] = make_int2(src | ((dst & 255) << 16), e);
  }
}

// one block per bucket -> exact CSR (offs + s_se{src,eid} + csrpos[eid])
__global__ __launch_bounds__(256) void fine_csr_kernel(
    const int2* __restrict__ s_tmp, const int* __restrict__ coarse_offs,
    int2* __restrict__ s_se, int* __restrict__ csrpos,
    int* __restrict__ offs) {
  __shared__ int cnt[256], sc[256], cur[256];
  int t = threadIdx.x, b = blockIdx.x;
  int lo = coarse_offs[b], hi = coarse_offs[b + 1];
  cnt[t] = 0;
  __syncthreads();
  for (int p = lo + t; p < hi; p += 256)
    atomicAdd(&cnt[(s_tmp[p].x >> 16) & 255], 1);
  __syncthreads();
  int myc = cnt[t];
  sc[t] = myc;
  __syncthreads();
  for (int d = 1; d < 256; d <<= 1) {
    int v = (t >= d) ? sc[t - d] : 0;
    __syncthreads();
    sc[t] += v;
    __syncthreads();
  }
  int excl = sc[t] - myc;
  cur[t] = lo + excl;
  int gd = b * 256 + t;
  if (gd <= NN) offs[gd] = lo + excl;
  __syncthreads();
  for (int p = lo + t; p < hi; p += 256) {
    int2 m = s_tmp[p];
    int pos = atomicAdd(&cur[(m.x >> 16) & 255], 1);
    s_se[pos] = make_int2(m.x & 0xFFFF, m.y);
    csrpos[m.y] = pos;
  }
}

// ---------------- Kernel 2c: place edge_attr as f16 at final CSR slot --
// sequential edge_attr read (the only pass over it in the build), one
// scattered 32B write per edge.
__global__ __launch_bounds__(256) void ea_place_kernel(
    const float* __restrict__ edge_attr, const int* __restrict__ csrpos,
    uint4* __restrict__ s_ea4) {
  int e = blockIdx.x * 256 + threadIdx.x;
  const float4* eap = (const float4*)(edge_attr + (size_t)e * 16);
  float4 a = eap[0], bb = eap[1], c = eap[2], d = eap[3];
  uint4 u0, u1;
  __half2 hh;
  hh = __floats2half2_rn(a.x, a.y);   u0.x = *(unsigned*)&hh;
  hh = __floats2half2_rn(a.z, a.w);   u0.y = *(unsigned*)&hh;
  hh = __floats2half2_rn(bb.x, bb.y); u0.z = *(unsigned*)&hh;
  hh = __floats2half2_rn(bb.z, bb.w); u0.w = *(unsigned*)&hh;
  hh = __floats2half2_rn(c.x, c.y);   u1.x = *(unsigned*)&hh;
  hh = __floats2half2_rn(c.z, c.w);   u1.y = *(unsigned*)&hh;
  hh = __floats2half2_rn(d.x, d.y);   u1.z = *(unsigned*)&hh;
  hh = __floats2half2_rn(d.z, d.w);   u1.w = *(unsigned*)&hh;
  int pos = csrpos[e];
  s_ea4[(size_t)pos * 2]     = u0;
  s_ea4[(size_t)pos * 2 + 1] = u1;
}

// ---------------- Kernel 3: aggregation + A/C epilogue -----------------
// one wave per dst node; 16 lanes/head; sequential s_se/s_ea; 8-edge ILP;
// DPP dot reduce (zero DS ops in loop); coalesced-scalar weight epilogue.
__global__ __launch_bounds__(256) void aggregate_kernel(
    const float* __restrict__ y, const float* __restrict__ qe,
    const float* __restrict__ u4, const float* __restrict__ w4,
    const float* __restrict__ x, const __half* __restrict__ s_ea,
    const int2* __restrict__ s_se,
    const float* __restrict__ We, const float* __restrict__ Wv,
    const float* __restrict__ bv,
    const float* __restrict__ Wskip, const float* __restrict__ bskip,
    const float* __restrict__ W1, const float* __restrict__ b1,
    const int* __restrict__ offs,
    __half* __restrict__ Ah, __half* __restrict__ Cbh) {
  int wave = threadIdx.x >> 6, lane = threadIdx.x & 63;
  int n = blockIdx.x * 4 + wave;
  int h = lane >> 4, t = lane & 15;
  int base = h * 32 + t;
  int gb = lane & 48;

  float yt = y[n * 64 + lane];
  float qet = qe[n * 64 + lane];
  float u_n = u4[n * 4 + h];
  int off = offs[n], end = offs[n + 1];

  float s = 0.f, ax = 0.f, ae = 0.f;
  int j = off;
  for (; j + 8 <= end; j += 8) {
    const uint4* sp = (const uint4*)&s_se[j];
    uint4 sa = sp[0], sb = sp[1], sc4 = sp[2], sd = sp[3];
    int src[8] = {(int)sa.x, (int)sa.z, (int)sb.x, (int)sb.z,
                  (int)sc4.x, (int)sc4.z, (int)sd.x, (int)sd.z};
    float xs[8], ea[8], uw[8];
#pragma unroll
    for (int u = 0; u < 8; u++) {
      xs[u] = x[(unsigned)src[u] * 16u + (unsigned)t];
      ea[u] = __half2float(s_ea[(size_t)(j + u) * 16 + t]);
      uw[u] = w4[(unsigned)src[u] * 4u + (unsigned)h];
    }
    float p[8];
#pragma unroll
    for (int u = 0; u < 8; u++) p[u] = fmaf(yt, xs[u], qet * ea[u]);
#pragma unroll
    for (int u = 0; u < 8; u++) p[u] = row16_reduce(p[u]);
#pragma unroll
    for (int u = 0; u < 8; u++) {
      float wgt = exp2f(p[u] + u_n + uw[u]);
      s += wgt;
      ax = fmaf(wgt, xs[u], ax);
      ae = fmaf(wgt, ea[u], ae);
    }
  }
  for (; j < end; j++) {
    int srcu = s_se[j].x;
    float xs = x[(unsigned)srcu * 16u + (unsigned)t];
    float ea_ = __half2float(s_ea[(size_t)j * 16 + t]);
    float uw = w4[(unsigned)srcu * 4u + (unsigned)h];
    float p = fmaf(yt, xs, qet * ea_);
    p = row16_reduce(p);
    float wgt = exp2f(p + u_n + uw);
    s += wgt;
    ax = fmaf(wgt, xs, ax);
    ae = fmaf(wgt, ea_, ae);
  }

  float inv = (end > off) ? 1.f / s : 0.f;
  float dflag = (end > off) ? 1.f : 0.f;
  float axn = ax * inv, aen = ae * inv;
  float r0 = dflag * bv[base], r1 = dflag * bv[base + 16];
#pragma unroll
  for (int i = 0; i < 16; i++) {
    float axi = __shfl(axn, gb | i);
    float aei = __shfl(aen, gb | i);
    r0 += axi * Wv[i * 128 + base]      + aei * We[i * 128 + base];
    r1 += axi * Wv[i * 128 + base + 16] + aei * We[i * 128 + base + 16];
  }
  // mean over heads
  r0 += __shfl_xor(r0, 16); r0 += __shfl_xor(r0, 32);
  r1 += __shfl_xor(r1, 16); r1 += __shfl_xor(r1, 32);

  // skip connection
  float sk0 = bskip[t], sk1 = bskip[t + 16];
#pragma unroll
  for (int i = 0; i < 16; i++) {
    float xi = x[n * 16 + i];
    sk0 += xi * Wskip[i * 32 + t];
    sk1 += xi * Wskip[i * 32 + t + 16];
  }
  float o0 = 0.25f * r0 + sk0;  // out[n][t]
  float o1 = 0.25f * r1 + sk1;  // out[n][t+16]

  // A[n][jj] = out@W1[0:32]; Cb[n][jj] = out@W1[48:80] + b1  (stored f16)
  int jj = lane & 31;
  int roff = (lane < 32) ? 0 : 48;
  float acc = (lane < 32) ? 0.f : b1[jj];
#pragma unroll
  for (int i = 0; i < 16; i++) {
    float oi = __shfl(o0, i);
    acc += oi * W1[(roff + i) * 32 + jj];
  }
#pragma unroll
  for (int i = 0; i < 16; i++) {
    float oi = __shfl(o1, i);
    acc += oi * W1[(roff + 16 + i) * 32 + jj];
  }
  float nb = __shfl_xor(acc, 1);
  if ((lane & 1) == 0) {
    __half2 hh = __floats2half2_rn(acc, nb);
    if (lane < 32) *(__half2*)(Ah  + n * 32 + jj) = hh;
    else           *(__half2*)(Cbh + n * 32 + jj) = hh;
  }
}

// ---------------- Kernel 4: per-edge MLP, CSR order --------------------
// wave per dst node, 2 edges per iter. Cb invariant (f16), s_ea sequential
// f16, A f16 gather; reduce = 4 DPP + 1 shfl (was 5 shfl).
__global__ __launch_bounds__(256) void mlp_kernel(
    const int2* __restrict__ s_se, const __half* __restrict__ s_ea,
    const int* __restrict__ offs,
    const __half* __restrict__ Ah, const __half* __restrict__ Cbh,
    const float* __restrict__ W1, const float* __restrict__ W2,
    const float* __restrict__ b2v, float* __restrict__ out) {
  int wave = threadIdx.x >> 6, lane = threadIdx.x & 63;
  int n = blockIdx.x * 4 + wave;
  int g = lane >> 5, l = lane & 31;

  float w1e[16];
#pragma unroll
  for (int i = 0; i < 16; i++) w1e[i] = W1[(32 + i) * 32 + l];
  float w2j = W2[l];
  float b2s = b2v[0];
  float cb = __half2float(Cbh[n * 32 + l]);
  int off = offs[n], end = offs[n + 1];

  for (int p = off + g; p < end; p += 2) {
    int2 se = s_se[p];
    float a = __half2float(Ah[(unsigned)se.x * 32u + l]);
    const uint4* eap = (const uint4*)(s_ea + (size_t)p * 16);
    uint4 u0 = eap[0], u1 = eap[1];
    float hsum = a + cb;
    const __half2* hp0 = (const __half2*)&u0;
    const __half2* hp1 = (const __half2*)&u1;
#pragma unroll
    for (int i = 0; i < 4; i++) {
      float2 f0 = __half22float2(hp0[i]);
      hsum += f0.x * w1e[2 * i] + f0.y * w1e[2 * i + 1];
      float2 f1 = __half22float2(hp1[i]);
      hsum += f1.x * w1e[8 + 2 * i] + f1.y * w1e[8 + 2 * i + 1];
    }
    float hv = fmaxf(hsum, 0.f) * w2j;
    hv = row16_reduce(hv);      // DPP, VALU pipe
    hv += __shfl_xor(hv, 16);   // cross-row within 32-lane group
    if (l == 0) out[se.y] = hv + b2s;
  }
}

// ---------------- launch -----------------------------------------------
extern "C" void kernel_launch(void* const* d_in, const int* in_sizes, int n_in,
                              void* d_out, int out_size, void* d_ws, size_t ws_size,
                              hipStream_t stream) {
  const float* x         = (const float*)d_in[0];
  const int*   ei        = (const int*)d_in[1];
  const float* edge_attr = (const float*)d_in[2];
  const float* Wq = (const float*)d_in[3],  *bq = (const float*)d_in[4];
  const float* Wk = (const float*)d_in[5],  *bk = (const float*)d_in[6];
  const float* Wv = (const float*)d_in[7],  *bv = (const float*)d_in[8];
  const float* We = (const float*)d_in[9];
  const float* Wskip = (const float*)d_in[10], *bskip = (const float*)d_in[11];
  const float* W1 = (const float*)d_in[12], *b1 = (const float*)d_in[13];
  const float* W2 = (const float*)d_in[14], *b2 = (const float*)d_in[15];
  float* out = (float*)d_out;

  // workspace (~70 MB); Ah/Cbh ALIAS s_tmp (dead after fine_csr)
  char* w = (char*)d_ws;
  float*   y    = (float*)w;            w += (size_t)NN * 64 * 4;   // 12.8 MB
  float*   qe   = (float*)w;            w += (size_t)NN * 64 * 4;   // 12.8 MB
  float*   u4   = (float*)w;            w += (size_t)NN * 4 * 4;    // 0.8 MB
  float*   w4   = (float*)w;            w += (size_t)NN * 4 * 4;    // 0.8 MB
  int2*    s_se = (int2*)w;             w += (size_t)NE * 8;        // 6.4 MB
  int2*    s_tmp = (int2*)w;            // 6.4 MB (Ah, Cbh alias inside)
  __half*  Ah   = (__half*)s_tmp;                           // 3.2 MB
  __half*  Cbh  = (__half*)((char*)s_tmp + (size_t)NN * 32 * 2); // 3.2 MB
  w += (size_t)NE * 8;
  uint4*   s_ea4 = (uint4*)w;           w += (size_t)NE * 32;       // 25.6 MB
  int*     csrpos = (int*)w;            w += (size_t)NE * 4;        // 3.2 MB
  int*     hist_all = (int*)w;          w += (size_t)256 * 256 * 4; // 256 KB
  int*     btot = (int*)w;              w += 256 * 4;
  int*     coarse_offs = (int*)w;       w += 256 * 4;
  int*     offs = (int*)w;              w += ((size_t)NN + 1) * 4;
  float*   P    = (float*)w;            w += (size_t)P_TOTAL * 4;

  precompute_kernel<<<1, 256, 0, stream>>>(Wq, Wk, bq, bk, We, P);
  node_linear_kernel<<<NODE_BLOCKS + 256, 256, 0, stream>>>(
      x, P, ei, hist_all, y, qe, u4, w4);
  scan_buckets_kernel<<<49, 256, 0, stream>>>(hist_all, btot);
  tiny_scan_kernel<<<1, 256, 0, stream>>>(btot, coarse_offs);
  bucket_scatter_kernel<<<256, 256, 0, stream>>>(ei, hist_all, coarse_offs,
                                                 s_tmp);
  fine_csr_kernel<<<NB, 256, 0, stream>>>(s_tmp, coarse_offs, s_se, csrpos,
                                          offs);
  ea_place_kernel<<<NE / 256, 256, 0, stream>>>(edge_attr, csrpos, s_ea4);
  aggregate_kernel<<<NN / 4, 256, 0, stream>>>(y, qe, u4, w4, x,
                                               (const __half*)s_ea4, s_se,
                                               We, Wv, bv, Wskip, bskip, W1, b1,
                                               offs, Ah, Cbh);
  mlp_kernel<<<NN / 4, 256, 0, stream>>>(s_se, (const __half*)s_ea4, offs,
                                         Ah, Cbh, W1, W2, b2, out);
}

// Round 17
// 229.297 us; speedup vs baseline: 1.6961x; 1.1073x over previous
//
#include <hip/hip_runtime.h>
#include <hip/hip_fp16.h>

#define NN 50000
#define NE 800000
// IN_C=16, EDGE_IN=16, HID=32, HEADS=4, HC=128
#define NB 196            // coarse buckets = ceil(NN/256)
#define EPB 3125          // edges per bucket-build block (NE/256)
#define NODE_BLOCKS 12500 // NN/4

// scale folded into all alpha components: log2(e)/sqrt(32)
#define SL 0.25506413f

// packed table offsets (floats)
#define PMV 0
#define MEV 1024
#define BEV 2048
#define UPV 2112
#define WPV 2176
#define WCV 2240
#define P_TOTAL 2304

// DPP-based add over lanes: quad xor1=0xB1, xor2=0x4E, row_ror:4=0x124,
// row_ror:8=0x128 (rows are 16 lanes = one head group). VALU-pipe only.
template <int CTRL>
__device__ __forceinline__ float dpp_add(float v) {
  int m = __builtin_amdgcn_update_dpp(0, __builtin_bit_cast(int, v), CTRL, 0xF, 0xF, true);
  return v + __builtin_bit_cast(float, m);
}
__device__ __forceinline__ float row16_reduce(float v) {
  v = dpp_add<0xB1>(v);
  v = dpp_add<0x4E>(v);
  v = dpp_add<0x124>(v);
  v = dpp_add<0x128>(v);
  return v;
}

// ---------------- Kernel 0: weight precompute --------------------------
__global__ __launch_bounds__(256) void precompute_kernel(
    const float* __restrict__ Wq, const float* __restrict__ Wk,
    const float* __restrict__ bq, const float* __restrict__ bk,
    const float* __restrict__ We, float* __restrict__ P) {
  int t = threadIdx.x;
  for (int idx = t; idx < 1024; idx += 256) {
    int lane = idx >> 4, i = idx & 15;
    int h = lane >> 4, tt = lane & 15;
    float am = 0.f, ae = 0.f;
#pragma unroll
    for (int c = 0; c < 32; c++) {
      float wq = Wq[i * 128 + h * 32 + c];
      am += wq * Wk[tt * 128 + h * 32 + c];
      ae += wq * We[tt * 128 + h * 32 + c];
    }
    P[PMV + idx] = am * SL;
    P[MEV + idx] = ae * SL;
  }
  if (t < 64) {
    int h = t >> 4, tt = t & 15;
    float be = 0.f, up = 0.f, wp = 0.f;
#pragma unroll
    for (int c = 0; c < 32; c++) {
      be += bq[h * 32 + c] * We[tt * 128 + h * 32 + c];
      up += Wq[tt * 128 + h * 32 + c] * bk[h * 32 + c];
      wp += bq[h * 32 + c] * Wk[tt * 128 + h * 32 + c];
    }
    P[BEV + t] = be * SL;
    P[UPV + t] = up * SL;
    P[WPV + t] = wp * SL;
  }
  if (t < 4) {
    float wc = 0.f;
#pragma unroll
    for (int c = 0; c < 32; c++) wc += bq[t * 32 + c] * bk[t * 32 + c];
    P[WCV + t] = wc * SL;
  }
}

// ---------------- Kernel 1: node precompute + coarse hist (fused) ------
__global__ __launch_bounds__(256) void node_linear_kernel(
    const float* __restrict__ x, const float* __restrict__ P,
    const int* __restrict__ ei, int* __restrict__ hist_all,
    float* __restrict__ y, float* __restrict__ qe,
    float* __restrict__ u4) {
  __shared__ int hist[NB];
  if (blockIdx.x >= NODE_BLOCKS) {
    int b = blockIdx.x - NODE_BLOCKS;  // [0,256)
    int t = threadIdx.x;
    if (t < NB) hist[t] = 0;
    __syncthreads();
    int base = b * EPB;
    for (int i = t; i < EPB; i += 256)
      atomicAdd(&hist[ei[NE + base + i] >> 8], 1);
    __syncthreads();
    if (t < NB) hist_all[t * 256 + b] = hist[t];
    return;
  }
  int wave = threadIdx.x >> 6;
  int lane = threadIdx.x & 63;
  int n = blockIdx.x * 4 + wave;
  int h = lane >> 4, t = lane & 15;

  const float4* xp = (const float4*)(x + n * 16);
  float4 X0 = xp[0], X1 = xp[1], X2 = xp[2], X3 = xp[3];
  float xr[16] = {X0.x, X0.y, X0.z, X0.w, X1.x, X1.y, X1.z, X1.w,
                  X2.x, X2.y, X2.z, X2.w, X3.x, X3.y, X3.z, X3.w};

  const float4* pm = (const float4*)(P + PMV) + lane * 4;
  const float4* me = (const float4*)(P + MEV) + lane * 4;
  float yt = 0.f, qv = P[BEV + lane];
#pragma unroll
  for (int i4 = 0; i4 < 4; i4++) {
    float4 m = pm[i4], e = me[i4];
    yt += xr[4 * i4] * m.x + xr[4 * i4 + 1] * m.y
        + xr[4 * i4 + 2] * m.z + xr[4 * i4 + 3] * m.w;
    qv += xr[4 * i4] * e.x + xr[4 * i4 + 1] * e.y
        + xr[4 * i4 + 2] * e.z + xr[4 * i4 + 3] * e.w;
  }
  y[n * 64 + lane] = yt;
  qe[n * 64 + lane] = qv;

  float pu = P[UPV + lane] * xr[t];
  pu = row16_reduce(pu);
  if (t == 0) u4[n * 4 + h] = pu;
}

// ---------------- CSR build ---------------------------------------------
__global__ __launch_bounds__(256) void scan_buckets_kernel(
    int* __restrict__ hist_all, int* __restrict__ btot) {
  int wv = blockIdx.x * 4 + (threadIdx.x >> 6);
  int l = threadIdx.x & 63;
  if (wv >= NB) return;
  int base = wv * 256;
  int run = 0;
#pragma unroll
  for (int c = 0; c < 4; c++) {
    int v = hist_all[base + c * 64 + l];
    int orig = v;
#pragma unroll
    for (int d = 1; d < 64; d <<= 1) {
      int u = __shfl_up(v, d);
      if (l >= d) v += u;
    }
    hist_all[base + c * 64 + l] = run + v - orig;
    run += __shfl(v, 63);
  }
  if (l == 0) btot[wv] = run;
}

__global__ __launch_bounds__(256) void tiny_scan_kernel(
    const int* __restrict__ btot, int* __restrict__ coarse_offs) {
  __shared__ int sc[256];
  int t = threadIdx.x;
  int v = (t < NB) ? btot[t] : 0;
  sc[t] = v;
  __syncthreads();
  for (int d = 1; d < 256; d <<= 1) {
    int u = (t >= d) ? sc[t - d] : 0;
    __syncthreads();
    sc[t] += u;
    __syncthreads();
  }
  if (t < NB) coarse_offs[t] = sc[t] - v;
  if (t == NB - 1) coarse_offs[NB] = sc[t];
}

// scatter edge META only (8B) into coarse-bucket order
__global__ __launch_bounds__(256) void bucket_scatter_kernel(
    const int* __restrict__ ei, const int* __restrict__ cursor_all,
    const int* __restrict__ coarse_offs, int2* __restrict__ s_tmp) {
  __shared__ int cur[NB];
  int t = threadIdx.x, b = blockIdx.x;
  if (t < NB) cur[t] = cursor_all[t * 256 + b] + coarse_offs[t];
  __syncthreads();
  int base = b * EPB;
  for (int i = t; i < EPB; i += 256) {
    int e = base + i;
    int src = ei[e], dst = ei[NE + e];
    int pos = atomicAdd(&cur[dst >> 8], 1);
    s_tmp[pos] = make_int2(src | ((dst & 255) << 16), e);
  }
}

// one block per bucket -> exact CSR (offs + s_se{src,eid} + csrpos[eid])
__global__ __launch_bounds__(256) void fine_csr_kernel(
    const int2* __restrict__ s_tmp, const int* __restrict__ coarse_offs,
    int2* __restrict__ s_se, int* __restrict__ csrpos,
    int* __restrict__ offs) {
  __shared__ int cnt[256], sc[256], cur[256];
  int t = threadIdx.x, b = blockIdx.x;
  int lo = coarse_offs[b], hi = coarse_offs[b + 1];
  cnt[t] = 0;
  __syncthreads();
  for (int p = lo + t; p < hi; p += 256)
    atomicAdd(&cnt[(s_tmp[p].x >> 16) & 255], 1);
  __syncthreads();
  int myc = cnt[t];
  sc[t] = myc;
  __syncthreads();
  for (int d = 1; d < 256; d <<= 1) {
    int v = (t >= d) ? sc[t - d] : 0;
    __syncthreads();
    sc[t] += v;
    __syncthreads();
  }
  int excl = sc[t] - myc;
  cur[t] = lo + excl;
  int gd = b * 256 + t;
  if (gd <= NN) offs[gd] = lo + excl;
  __syncthreads();
  for (int p = lo + t; p < hi; p += 256) {
    int2 m = s_tmp[p];
    int pos = atomicAdd(&cur[(m.x >> 16) & 255], 1);
    s_se[pos] = make_int2(m.x & 0xFFFF, m.y);
    csrpos[m.y] = pos;
  }
}

// ---------------- Kernel 2c: place edge_attr as f16 at final CSR slot --
__global__ __launch_bounds__(256) void ea_place_kernel(
    const float* __restrict__ edge_attr, const int* __restrict__ csrpos,
    uint4* __restrict__ s_ea4) {
  int e = blockIdx.x * 256 + threadIdx.x;
  const float4* eap = (const float4*)(edge_attr + (size_t)e * 16);
  float4 a = eap[0], bb = eap[1], c = eap[2], d = eap[3];
  uint4 u0, u1;
  __half2 hh;
  hh = __floats2half2_rn(a.x, a.y);   u0.x = *(unsigned*)&hh;
  hh = __floats2half2_rn(a.z, a.w);   u0.y = *(unsigned*)&hh;
  hh = __floats2half2_rn(bb.x, bb.y); u0.z = *(unsigned*)&hh;
  hh = __floats2half2_rn(bb.z, bb.w); u0.w = *(unsigned*)&hh;
  hh = __floats2half2_rn(c.x, c.y);   u1.x = *(unsigned*)&hh;
  hh = __floats2half2_rn(c.z, c.w);   u1.y = *(unsigned*)&hh;
  hh = __floats2half2_rn(d.x, d.y);   u1.z = *(unsigned*)&hh;
  hh = __floats2half2_rn(d.z, d.w);   u1.w = *(unsigned*)&hh;
  int pos = csrpos[e];
  s_ea4[(size_t)pos * 2]     = u0;
  s_ea4[(size_t)pos * 2 + 1] = u1;
}

// ---------------- Kernel 3: aggregation + A/C epilogue -----------------
// one wave per dst node; 16 lanes/head; sequential s_se/s_ea; 8-edge ILP;
// DPP dot reduce; w4 FOLDED into the dot (yt2 = yt + WPV[lane]), so the
// loop has NO per-src scalar gather.
__global__ __launch_bounds__(256) void aggregate_kernel(
    const float* __restrict__ y, const float* __restrict__ qe,
    const float* __restrict__ u4,
    const float* __restrict__ x, const __half* __restrict__ s_ea,
    const int2* __restrict__ s_se, const float* __restrict__ P,
    const float* __restrict__ We, const float* __restrict__ Wv,
    const float* __restrict__ bv,
    const float* __restrict__ Wskip, const float* __restrict__ bskip,
    const float* __restrict__ W1, const float* __restrict__ b1,
    const int* __restrict__ offs,
    __half* __restrict__ Ah, __half* __restrict__ Cbh) {
  int wave = threadIdx.x >> 6, lane = threadIdx.x & 63;
  int n = blockIdx.x * 4 + wave;
  int h = lane >> 4, t = lane & 15;
  int base = h * 32 + t;
  int gb = lane & 48;

  float yt2 = y[n * 64 + lane] + P[WPV + lane];   // fold bq.k term
  float qet = qe[n * 64 + lane];
  float un_wc = u4[n * 4 + h] + P[WCV + h];       // per-node constant
  int off = offs[n], end = offs[n + 1];

  float s = 0.f, ax = 0.f, ae = 0.f;
  int j = off;
  for (; j + 8 <= end; j += 8) {
    const uint4* sp = (const uint4*)&s_se[j];
    uint4 sa = sp[0], sb = sp[1], sc4 = sp[2], sd = sp[3];
    int src[8] = {(int)sa.x, (int)sa.z, (int)sb.x, (int)sb.z,
                  (int)sc4.x, (int)sc4.z, (int)sd.x, (int)sd.z};
    float xs[8], ea[8];
#pragma unroll
    for (int u = 0; u < 8; u++) {
      xs[u] = x[(unsigned)src[u] * 16u + (unsigned)t];
      ea[u] = __half2float(s_ea[(size_t)(j + u) * 16 + t]);
    }
    float p[8];
#pragma unroll
    for (int u = 0; u < 8; u++) p[u] = fmaf(yt2, xs[u], qet * ea[u]);
#pragma unroll
    for (int u = 0; u < 8; u++) p[u] = row16_reduce(p[u]);
#pragma unroll
    for (int u = 0; u < 8; u++) {
      float wgt = exp2f(p[u] + un_wc);
      s += wgt;
      ax = fmaf(wgt, xs[u], ax);
      ae = fmaf(wgt, ea[u], ae);
    }
  }
  for (; j < end; j++) {
    int srcu = s_se[j].x;
    float xs = x[(unsigned)srcu * 16u + (unsigned)t];
    float ea_ = __half2float(s_ea[(size_t)j * 16 + t]);
    float p = fmaf(yt2, xs, qet * ea_);
    p = row16_reduce(p);
    float wgt = exp2f(p + un_wc);
    s += wgt;
    ax = fmaf(wgt, xs, ax);
    ae = fmaf(wgt, ea_, ae);
  }

  float inv = (end > off) ? 1.f / s : 0.f;
  float dflag = (end > off) ? 1.f : 0.f;
  float axn = ax * inv, aen = ae * inv;
  float r0 = dflag * bv[base], r1 = dflag * bv[base + 16];
#pragma unroll
  for (int i = 0; i < 16; i++) {
    float axi = __shfl(axn, gb | i);
    float aei = __shfl(aen, gb | i);
    r0 += axi * Wv[i * 128 + base]      + aei * We[i * 128 + base];
    r1 += axi * Wv[i * 128 + base + 16] + aei * We[i * 128 + base + 16];
  }
  // mean over heads
  r0 += __shfl_xor(r0, 16); r0 += __shfl_xor(r0, 32);
  r1 += __shfl_xor(r1, 16); r1 += __shfl_xor(r1, 32);

  // skip connection
  float sk0 = bskip[t], sk1 = bskip[t + 16];
#pragma unroll
  for (int i = 0; i < 16; i++) {
    float xi = x[n * 16 + i];
    sk0 += xi * Wskip[i * 32 + t];
    sk1 += xi * Wskip[i * 32 + t + 16];
  }
  float o0 = 0.25f * r0 + sk0;  // out[n][t]
  float o1 = 0.25f * r1 + sk1;  // out[n][t+16]

  // A[n][jj] = out@W1[0:32]; Cb[n][jj] = out@W1[48:80] + b1  (stored f16)
  int jj = lane & 31;
  int roff = (lane < 32) ? 0 : 48;
  float acc = (lane < 32) ? 0.f : b1[jj];
#pragma unroll
  for (int i = 0; i < 16; i++) {
    float oi = __shfl(o0, i);
    acc += oi * W1[(roff + i) * 32 + jj];
  }
#pragma unroll
  for (int i = 0; i < 16; i++) {
    float oi = __shfl(o1, i);
    acc += oi * W1[(roff + 16 + i) * 32 + jj];
  }
  float nb = __shfl_xor(acc, 1);
  if ((lane & 1) == 0) {
    __half2 hh = __floats2half2_rn(acc, nb);
    if (lane < 32) *(__half2*)(Ah  + n * 32 + jj) = hh;
    else           *(__half2*)(Cbh + n * 32 + jj) = hh;
  }
}

// ---------------- Kernel 4: per-edge MLP, CSR order, 2-edge ILP --------
// wave per dst node, two 32-lane groups; each group processes 2 edges per
// iteration (independent load chains). Reduce = 4 DPP + 1 shfl.
__global__ __launch_bounds__(256) void mlp_kernel(
    const int2* __restrict__ s_se, const __half* __restrict__ s_ea,
    const int* __restrict__ offs,
    const __half* __restrict__ Ah, const __half* __restrict__ Cbh,
    const float* __restrict__ W1, const float* __restrict__ W2,
    const float* __restrict__ b2v, float* __restrict__ out) {
  int wave = threadIdx.x >> 6, lane = threadIdx.x & 63;
  int n = blockIdx.x * 4 + wave;
  int g = lane >> 5, l = lane & 31;

  float w1e[16];
#pragma unroll
  for (int i = 0; i < 16; i++) w1e[i] = W1[(32 + i) * 32 + l];
  float w2j = W2[l];
  float b2s = b2v[0];
  float cb = __half2float(Cbh[n * 32 + l]);
  int off = offs[n], end = offs[n + 1];

  int p = off + g;
  for (; p + 2 < end; p += 4) {   // 2 edges per group per iter
    int2 se0 = s_se[p];
    int2 se1 = s_se[p + 2];
    float a0 = __half2float(Ah[(unsigned)se0.x * 32u + l]);
    float a1 = __half2float(Ah[(unsigned)se1.x * 32u + l]);
    const uint4* e0p = (const uint4*)(s_ea + (size_t)p * 16);
    const uint4* e1p = (const uint4*)(s_ea + (size_t)(p + 2) * 16);
    uint4 u00 = e0p[0], u01 = e0p[1];
    uint4 u10 = e1p[0], u11 = e1p[1];
    float h0 = a0 + cb, h1 = a1 + cb;
    const __half2* q00 = (const __half2*)&u00;
    const __half2* q01 = (const __half2*)&u01;
    const __half2* q10 = (const __half2*)&u10;
    const __half2* q11 = (const __half2*)&u11;
#pragma unroll
    for (int i = 0; i < 4; i++) {
      float2 f;
      f = __half22float2(q00[i]); h0 += f.x * w1e[2*i]   + f.y * w1e[2*i+1];
      f = __half22float2(q01[i]); h0 += f.x * w1e[8+2*i] + f.y * w1e[8+2*i+1];
      f = __half22float2(q10[i]); h1 += f.x * w1e[2*i]   + f.y * w1e[2*i+1];
      f = __half22float2(q11[i]); h1 += f.x * w1e[8+2*i] + f.y * w1e[8+2*i+1];
    }
    float v0 = fmaxf(h0, 0.f) * w2j;
    float v1 = fmaxf(h1, 0.f) * w2j;
    v0 = row16_reduce(v0); v1 = row16_reduce(v1);
    v0 += __shfl_xor(v0, 16); v1 += __shfl_xor(v1, 16);
    if (l == 0) {
      out[se0.y] = v0 + b2s;
      out[se1.y] = v1 + b2s;
    }
  }
  if (p < end) {
    int2 se = s_se[p];
    float a = __half2float(Ah[(unsigned)se.x * 32u + l]);
    const uint4* eap = (const uint4*)(s_ea + (size_t)p * 16);
    uint4 u0 = eap[0], u1 = eap[1];
    float hsum = a + cb;
    const __half2* hp0 = (const __half2*)&u0;
    const __half2* hp1 = (const __half2*)&u1;
#pragma unroll
    for (int i = 0; i < 4; i++) {
      float2 f0 = __half22float2(hp0[i]);
      hsum += f0.x * w1e[2 * i] + f0.y * w1e[2 * i + 1];
      float2 f1 = __half22float2(hp1[i]);
      hsum += f1.x * w1e[8 + 2 * i] + f1.y * w1e[8 + 2 * i + 1];
    }
    float hv = fmaxf(hsum, 0.f) * w2j;
    hv = row16_reduce(hv);
    hv += __shfl_xor(hv, 16);
    if (l == 0) out[se.y] = hv + b2s;
  }
}

// ---------------- launch -----------------------------------------------
extern "C" void kernel_launch(void* const* d_in, const int* in_sizes, int n_in,
                              void* d_out, int out_size, void* d_ws, size_t ws_size,
                              hipStream_t stream) {
  const float* x         = (const float*)d_in[0];
  const int*   ei        = (const int*)d_in[1];
  const float* edge_attr = (const float*)d_in[2];
  const float* Wq = (const float*)d_in[3],  *bq = (const float*)d_in[4];
  const float* Wk = (const float*)d_in[5],  *bk = (const float*)d_in[6];
  const float* Wv = (const float*)d_in[7],  *bv = (const float*)d_in[8];
  const float* We = (const float*)d_in[9];
  const float* Wskip = (const float*)d_in[10], *bskip = (const float*)d_in[11];
  const float* W1 = (const float*)d_in[12], *b1 = (const float*)d_in[13];
  const float* W2 = (const float*)d_in[14], *b2 = (const float*)d_in[15];
  float* out = (float*)d_out;

  // workspace (~69 MB); Ah/Cbh ALIAS s_tmp (dead after fine_csr)
  char* w = (char*)d_ws;
  float*   y    = (float*)w;            w += (size_t)NN * 64 * 4;   // 12.8 MB
  float*   qe   = (float*)w;            w += (size_t)NN * 64 * 4;   // 12.8 MB
  float*   u4   = (float*)w;            w += (size_t)NN * 4 * 4;    // 0.8 MB
  int2*    s_se = (int2*)w;             w += (size_t)NE * 8;        // 6.4 MB
  int2*    s_tmp = (int2*)w;            // 6.4 MB (Ah, Cbh alias inside)
  __half*  Ah   = (__half*)s_tmp;                           // 3.2 MB
  __half*  Cbh  = (__half*)((char*)s_tmp + (size_t)NN * 32 * 2); // 3.2 MB
  w += (size_t)NE * 8;
  uint4*   s_ea4 = (uint4*)w;           w += (size_t)NE * 32;       // 25.6 MB
  int*     csrpos = (int*)w;            w += (size_t)NE * 4;        // 3.2 MB
  int*     hist_all = (int*)w;          w += (size_t)256 * 256 * 4; // 256 KB
  int*     btot = (int*)w;              w += 256 * 4;
  int*     coarse_offs = (int*)w;       w += 256 * 4;
  int*     offs = (int*)w;              w += ((size_t)NN + 1) * 4;
  float*   P    = (float*)w;            w += (size_t)P_TOTAL * 4;

  precompute_kernel<<<1, 256, 0, stream>>>(Wq, Wk, bq, bk, We, P);
  node_linear_kernel<<<NODE_BLOCKS + 256, 256, 0, stream>>>(
      x, P, ei, hist_all, y, qe, u4);
  scan_buckets_kernel<<<49, 256, 0, stream>>>(hist_all, btot);
  tiny_scan_kernel<<<1, 256, 0, stream>>>(btot, coarse_offs);
  bucket_scatter_kernel<<<256, 256, 0, stream>>>(ei, hist_all, coarse_offs,
                                                 s_tmp);
  fine_csr_kernel<<<NB, 256, 0, stream>>>(s_tmp, coarse_offs, s_se, csrpos,
                                          offs);
  ea_place_kernel<<<NE / 256, 256, 0, stream>>>(edge_attr, csrpos, s_ea4);
  aggregate_kernel<<<NN / 4, 256, 0, stream>>>(y, qe, u4, x,
                                               (const __half*)s_ea4, s_se, P,
                                               We, Wv, bv, Wskip, bskip, W1, b1,
                                               offs, Ah, Cbh);
  mlp_kernel<<<NN / 4, 256, 0, stream>>>(s_se, (const __half*)s_ea4, offs,
                                         Ah, Cbh, W1, W2, b2, out);
}

// Round 18
// 227.792 us; speedup vs baseline: 1.7073x; 1.0066x over previous
//
#include <hip/hip_runtime.h>
#include <hip/hip_fp16.h>

#define NN 50000
#define NE 800000
// IN_C=16, EDGE_IN=16, HID=32, HEADS=4, HC=128
#define NB 196            // coarse buckets = ceil(NN/256)
#define HB 800            // bucket-build blocks
#define EPB 1000          // edges per bucket-build block (NE/HB)
#define NODE_BLOCKS 12500 // NN/4

// scale folded into all alpha components: log2(e)/sqrt(32)
#define SL 0.25506413f

// packed table offsets (floats)
#define PMV 0
#define MEV 1024
#define BEV 2048
#define UPV 2112
#define WPV 2176
#define WCV 2240
#define P_TOTAL 2304

// DPP-based add over lanes: quad xor1=0xB1, xor2=0x4E, row_ror:4=0x124,
// row_ror:8=0x128 (rows are 16 lanes = one head group). VALU-pipe only.
template <int CTRL>
__device__ __forceinline__ float dpp_add(float v) {
  int m = __builtin_amdgcn_update_dpp(0, __builtin_bit_cast(int, v), CTRL, 0xF, 0xF, true);
  return v + __builtin_bit_cast(float, m);
}
__device__ __forceinline__ float row16_reduce(float v) {
  v = dpp_add<0xB1>(v);
  v = dpp_add<0x4E>(v);
  v = dpp_add<0x124>(v);
  v = dpp_add<0x128>(v);
  return v;
}

// ---------------- Kernel 0: weight precompute --------------------------
__global__ __launch_bounds__(256) void precompute_kernel(
    const float* __restrict__ Wq, const float* __restrict__ Wk,
    const float* __restrict__ bq, const float* __restrict__ bk,
    const float* __restrict__ We, float* __restrict__ P) {
  int t = threadIdx.x;
  for (int idx = t; idx < 1024; idx += 256) {
    int lane = idx >> 4, i = idx & 15;
    int h = lane >> 4, tt = lane & 15;
    float am = 0.f, ae = 0.f;
#pragma unroll
    for (int c = 0; c < 32; c++) {
      float wq = Wq[i * 128 + h * 32 + c];
      am += wq * Wk[tt * 128 + h * 32 + c];
      ae += wq * We[tt * 128 + h * 32 + c];
    }
    P[PMV + idx] = am * SL;
    P[MEV + idx] = ae * SL;
  }
  if (t < 64) {
    int h = t >> 4, tt = t & 15;
    float be = 0.f, up = 0.f, wp = 0.f;
#pragma unroll
    for (int c = 0; c < 32; c++) {
      be += bq[h * 32 + c] * We[tt * 128 + h * 32 + c];
      up += Wq[tt * 128 + h * 32 + c] * bk[h * 32 + c];
      wp += bq[h * 32 + c] * Wk[tt * 128 + h * 32 + c];
    }
    P[BEV + t] = be * SL;
    P[UPV + t] = up * SL;
    P[WPV + t] = wp * SL;
  }
  if (t < 4) {
    float wc = 0.f;
#pragma unroll
    for (int c = 0; c < 32; c++) wc += bq[t * 32 + c] * bk[t * 32 + c];
    P[WCV + t] = wc * SL;
  }
}

// ---------------- Kernel 1: node precompute + coarse hist (fused) ------
__global__ __launch_bounds__(256) void node_linear_kernel(
    const float* __restrict__ x, const float* __restrict__ P,
    const int* __restrict__ ei, int* __restrict__ hist_all,
    float* __restrict__ y, float* __restrict__ qe,
    float* __restrict__ u4) {
  __shared__ int hist[NB];
  if (blockIdx.x >= NODE_BLOCKS) {
    int b = blockIdx.x - NODE_BLOCKS;  // [0, HB)
    int t = threadIdx.x;
    if (t < NB) hist[t] = 0;
    __syncthreads();
    int base = b * EPB;
    for (int i = t; i < EPB; i += 256)
      atomicAdd(&hist[ei[NE + base + i] >> 8], 1);
    __syncthreads();
    if (t < NB) hist_all[t * HB + b] = hist[t];
    return;
  }
  int wave = threadIdx.x >> 6;
  int lane = threadIdx.x & 63;
  int n = blockIdx.x * 4 + wave;
  int h = lane >> 4, t = lane & 15;

  const float4* xp = (const float4*)(x + n * 16);
  float4 X0 = xp[0], X1 = xp[1], X2 = xp[2], X3 = xp[3];
  float xr[16] = {X0.x, X0.y, X0.z, X0.w, X1.x, X1.y, X1.z, X1.w,
                  X2.x, X2.y, X2.z, X2.w, X3.x, X3.y, X3.z, X3.w};

  const float4* pm = (const float4*)(P + PMV) + lane * 4;
  const float4* me = (const float4*)(P + MEV) + lane * 4;
  float yt = 0.f, qv = P[BEV + lane];
#pragma unroll
  for (int i4 = 0; i4 < 4; i4++) {
    float4 m = pm[i4], e = me[i4];
    yt += xr[4 * i4] * m.x + xr[4 * i4 + 1] * m.y
        + xr[4 * i4 + 2] * m.z + xr[4 * i4 + 3] * m.w;
    qv += xr[4 * i4] * e.x + xr[4 * i4 + 1] * e.y
        + xr[4 * i4 + 2] * e.z + xr[4 * i4 + 3] * e.w;
  }
  y[n * 64 + lane] = yt;
  qe[n * 64 + lane] = qv;

  float pu = P[UPV + lane] * xr[t];
  pu = row16_reduce(pu);
  if (t == 0) u4[n * 4 + h] = pu;
}

// ---------------- CSR build ---------------------------------------------
// one wave per bucket: guarded scan of its HB block-entries (in-place excl)
__global__ __launch_bounds__(256) void scan_buckets_kernel(
    int* __restrict__ hist_all, int* __restrict__ btot) {
  int wv = blockIdx.x * 4 + (threadIdx.x >> 6);
  int l = threadIdx.x & 63;
  if (wv >= NB) return;
  int base = wv * HB;
  int run = 0;
#pragma unroll
  for (int c = 0; c < (HB + 63) / 64; c++) {
    int idx = c * 64 + l;
    int v = (idx < HB) ? hist_all[base + idx] : 0;
    int orig = v;
#pragma unroll
    for (int d = 1; d < 64; d <<= 1) {
      int u = __shfl_up(v, d);
      if (l >= d) v += u;
    }
    if (idx < HB) hist_all[base + idx] = run + v - orig;
    run += __shfl(v, 63);
  }
  if (l == 0) btot[wv] = run;
}

__global__ __launch_bounds__(256) void tiny_scan_kernel(
    const int* __restrict__ btot, int* __restrict__ coarse_offs) {
  __shared__ int sc[256];
  int t = threadIdx.x;
  int v = (t < NB) ? btot[t] : 0;
  sc[t] = v;
  __syncthreads();
  for (int d = 1; d < 256; d <<= 1) {
    int u = (t >= d) ? sc[t - d] : 0;
    __syncthreads();
    sc[t] += u;
    __syncthreads();
  }
  if (t < NB) coarse_offs[t] = sc[t] - v;
  if (t == NB - 1) coarse_offs[NB] = sc[t];
}

// scatter edge META only (8B) into coarse-bucket order
__global__ __launch_bounds__(256) void bucket_scatter_kernel(
    const int* __restrict__ ei, const int* __restrict__ cursor_all,
    const int* __restrict__ coarse_offs, int2* __restrict__ s_tmp) {
  __shared__ int cur[NB];
  int t = threadIdx.x, b = blockIdx.x;
  if (t < NB) cur[t] = cursor_all[t * HB + b] + coarse_offs[t];
  __syncthreads();
  int base = b * EPB;
  for (int i = t; i < EPB; i += 256) {
    int e = base + i;
    int src = ei[e], dst = ei[NE + e];
    int pos = atomicAdd(&cur[dst >> 8], 1);
    s_tmp[pos] = make_int2(src | ((dst & 255) << 16), e);
  }
}

// one block per bucket -> exact CSR (offs + s_se{src,eid} + csrpos[eid])
__global__ __launch_bounds__(256) void fine_csr_kernel(
    const int2* __restrict__ s_tmp, const int* __restrict__ coarse_offs,
    int2* __restrict__ s_se, int* __restrict__ csrpos,
    int* __restrict__ offs) {
  __shared__ int cnt[256], sc[256], cur[256];
  int t = threadIdx.x, b = blockIdx.x;
  int lo = coarse_offs[b], hi = coarse_offs[b + 1];
  cnt[t] = 0;
  __syncthreads();
  for (int p = lo + t; p < hi; p += 256)
    atomicAdd(&cnt[(s_tmp[p].x >> 16) & 255], 1);
  __syncthreads();
  int myc = cnt[t];
  sc[t] = myc;
  __syncthreads();
  for (int d = 1; d < 256; d <<= 1) {
    int v = (t >= d) ? sc[t - d] : 0;
    __syncthreads();
    sc[t] += v;
    __syncthreads();
  }
  int excl = sc[t] - myc;
  cur[t] = lo + excl;
  int gd = b * 256 + t;
  if (gd <= NN) offs[gd] = lo + excl;
  __syncthreads();
  for (int p = lo + t; p < hi; p += 256) {
    int2 m = s_tmp[p];
    int pos = atomicAdd(&cur[(m.x >> 16) & 255], 1);
    s_se[pos] = make_int2(m.x & 0xFFFF, m.y);
    csrpos[m.y] = pos;
  }
}

// ---------------- Kernel 2c: place edge_attr as f16 at final CSR slot --
__global__ __launch_bounds__(256) void ea_place_kernel(
    const float* __restrict__ edge_attr, const int* __restrict__ csrpos,
    uint4* __restrict__ s_ea4) {
  int e = blockIdx.x * 256 + threadIdx.x;
  const float4* eap = (const float4*)(edge_attr + (size_t)e * 16);
  float4 a = eap[0], bb = eap[1], c = eap[2], d = eap[3];
  uint4 u0, u1;
  __half2 hh;
  hh = __floats2half2_rn(a.x, a.y);   u0.x = *(unsigned*)&hh;
  hh = __floats2half2_rn(a.z, a.w);   u0.y = *(unsigned*)&hh;
  hh = __floats2half2_rn(bb.x, bb.y); u0.z = *(unsigned*)&hh;
  hh = __floats2half2_rn(bb.z, bb.w); u0.w = *(unsigned*)&hh;
  hh = __floats2half2_rn(c.x, c.y);   u1.x = *(unsigned*)&hh;
  hh = __floats2half2_rn(c.z, c.w);   u1.y = *(unsigned*)&hh;
  hh = __floats2half2_rn(d.x, d.y);   u1.z = *(unsigned*)&hh;
  hh = __floats2half2_rn(d.z, d.w);   u1.w = *(unsigned*)&hh;
  int pos = csrpos[e];
  s_ea4[(size_t)pos * 2]     = u0;
  s_ea4[(size_t)pos * 2 + 1] = u1;
}

// ---------------- Kernel 3: aggregation + A/C epilogue -----------------
// one wave per dst node; 16 lanes/head; sequential s_se/s_ea; 8-edge ILP;
// DPP dot reduce; w4 folded into dot; epilogue broadcasts via wave-private
// LDS float4 reads (replaces 64 ds_bpermute with ~20 DS ops).
__global__ __launch_bounds__(256) void aggregate_kernel(
    const float* __restrict__ y, const float* __restrict__ qe,
    const float* __restrict__ u4,
    const float* __restrict__ x, const __half* __restrict__ s_ea,
    const int2* __restrict__ s_se, const float* __restrict__ P,
    const float* __restrict__ We, const float* __restrict__ Wv,
    const float* __restrict__ bv,
    const float* __restrict__ Wskip, const float* __restrict__ bskip,
    const float* __restrict__ W1, const float* __restrict__ b1,
    const int* __restrict__ offs,
    __half* __restrict__ Ah, __half* __restrict__ Cbh) {
  __shared__ float red[4][128];
  int wave = threadIdx.x >> 6, lane = threadIdx.x & 63;
  int n = blockIdx.x * 4 + wave;
  int h = lane >> 4, t = lane & 15;
  int base = h * 32 + t;

  float yt2 = y[n * 64 + lane] + P[WPV + lane];   // fold bq.k term
  float qet = qe[n * 64 + lane];
  float un_wc = u4[n * 4 + h] + P[WCV + h];       // per-node constant
  int off = offs[n], end = offs[n + 1];

  float s = 0.f, ax = 0.f, ae = 0.f;
  int j = off;
  for (; j + 8 <= end; j += 8) {
    const uint4* sp = (const uint4*)&s_se[j];
    uint4 sa = sp[0], sb = sp[1], sc4 = sp[2], sd = sp[3];
    int src[8] = {(int)sa.x, (int)sa.z, (int)sb.x, (int)sb.z,
                  (int)sc4.x, (int)sc4.z, (int)sd.x, (int)sd.z};
    float xs[8], ea[8];
#pragma unroll
    for (int u = 0; u < 8; u++) {
      xs[u] = x[(unsigned)src[u] * 16u + (unsigned)t];
      ea[u] = __half2float(s_ea[(size_t)(j + u) * 16 + t]);
    }
    float p[8];
#pragma unroll
    for (int u = 0; u < 8; u++) p[u] = fmaf(yt2, xs[u], qet * ea[u]);
#pragma unroll
    for (int u = 0; u < 8; u++) p[u] = row16_reduce(p[u]);
#pragma unroll
    for (int u = 0; u < 8; u++) {
      float wgt = exp2f(p[u] + un_wc);
      s += wgt;
      ax = fmaf(wgt, xs[u], ax);
      ae = fmaf(wgt, ea[u], ae);
    }
  }
  for (; j < end; j++) {
    int srcu = s_se[j].x;
    float xs = x[(unsigned)srcu * 16u + (unsigned)t];
    float ea_ = __half2float(s_ea[(size_t)j * 16 + t]);
    float p = fmaf(yt2, xs, qet * ea_);
    p = row16_reduce(p);
    float wgt = exp2f(p + un_wc);
    s += wgt;
    ax = fmaf(wgt, xs, ax);
    ae = fmaf(wgt, ea_, ae);
  }

  float inv = (end > off) ? 1.f / s : 0.f;
  float dflag = (end > off) ? 1.f : 0.f;
  float* rw = red[wave];
  rw[lane] = ax * inv;        // axn
  rw[64 + lane] = ae * inv;   // aen

  float r0 = dflag * bv[base], r1 = dflag * bv[base + 16];
  const float4* axp = (const float4*)&rw[h * 16];
  const float4* aep = (const float4*)&rw[64 + h * 16];
#pragma unroll
  for (int k = 0; k < 4; k++) {
    float4 a4 = axp[k], e4 = aep[k];
    int i0 = 4 * k;
    r0 += a4.x * Wv[(i0    ) * 128 + base] + e4.x * We[(i0    ) * 128 + base];
    r0 += a4.y * Wv[(i0 + 1) * 128 + base] + e4.y * We[(i0 + 1) * 128 + base];
    r0 += a4.z * Wv[(i0 + 2) * 128 + base] + e4.z * We[(i0 + 2) * 128 + base];
    r0 += a4.w * Wv[(i0 + 3) * 128 + base] + e4.w * We[(i0 + 3) * 128 + base];
    r1 += a4.x * Wv[(i0    ) * 128 + base + 16] + e4.x * We[(i0    ) * 128 + base + 16];
    r1 += a4.y * Wv[(i0 + 1) * 128 + base + 16] + e4.y * We[(i0 + 1) * 128 + base + 16];
    r1 += a4.z * Wv[(i0 + 2) * 128 + base + 16] + e4.z * We[(i0 + 2) * 128 + base + 16];
    r1 += a4.w * Wv[(i0 + 3) * 128 + base + 16] + e4.w * We[(i0 + 3) * 128 + base + 16];
  }
  // mean over heads
  r0 += __shfl_xor(r0, 16); r0 += __shfl_xor(r0, 32);
  r1 += __shfl_xor(r1, 16); r1 += __shfl_xor(r1, 32);

  // skip connection
  float sk0 = bskip[t], sk1 = bskip[t + 16];
#pragma unroll
  for (int i = 0; i < 16; i++) {
    float xi = x[n * 16 + i];
    sk0 += xi * Wskip[i * 32 + t];
    sk1 += xi * Wskip[i * 32 + t + 16];
  }
  float o0 = 0.25f * r0 + sk0;  // out[n][t]
  float o1 = 0.25f * r1 + sk1;  // out[n][t+16]

  // broadcast o0/o1 via LDS (axn/aen dead now; reuse rw[0..31])
  if (lane < 16) {
    rw[t] = o0;
    rw[16 + t] = o1;
  }

  // A[n][jj] = out@W1[0:32]; Cb[n][jj] = out@W1[48:80] + b1  (stored f16)
  int jj = lane & 31;
  int roff = (lane < 32) ? 0 : 48;
  float acc = (lane < 32) ? 0.f : b1[jj];
  const float4* op = (const float4*)rw;
#pragma unroll
  for (int k = 0; k < 4; k++) {
    float4 o4 = op[k];        // o0[4k..4k+3]
    int r = roff + 4 * k;
    acc += o4.x * W1[(r    ) * 32 + jj] + o4.y * W1[(r + 1) * 32 + jj]
         + o4.z * W1[(r + 2) * 32 + jj] + o4.w * W1[(r + 3) * 32 + jj];
  }
#pragma unroll
  for (int k = 0; k < 4; k++) {
    float4 o4 = op[4 + k];    // o1[4k..4k+3] -> rows roff+16+
    int r = roff + 16 + 4 * k;
    acc += o4.x * W1[(r    ) * 32 + jj] + o4.y * W1[(r + 1) * 32 + jj]
         + o4.z * W1[(r + 2) * 32 + jj] + o4.w * W1[(r + 3) * 32 + jj];
  }
  float nb = __shfl_xor(acc, 1);
  if ((lane & 1) == 0) {
    __half2 hh = __floats2half2_rn(acc, nb);
    if (lane < 32) *(__half2*)(Ah  + n * 32 + jj) = hh;
    else           *(__half2*)(Cbh + n * 32 + jj) = hh;
  }
}

// ---------------- Kernel 4: per-edge MLP, CSR order, 2-edge ILP --------
__global__ __launch_bounds__(256) void mlp_kernel(
    const int2* __restrict__ s_se, const __half* __restrict__ s_ea,
    const int* __restrict__ offs,
    const __half* __restrict__ Ah, const __half* __restrict__ Cbh,
    const float* __restrict__ W1, const float* __restrict__ W2,
    const float* __restrict__ b2v, float* __restrict__ out) {
  int wave = threadIdx.x >> 6, lane = threadIdx.x & 63;
  int n = blockIdx.x * 4 + wave;
  int g = lane >> 5, l = lane & 31;

  float w1e[16];
#pragma unroll
  for (int i = 0; i < 16; i++) w1e[i] = W1[(32 + i) * 32 + l];
  float w2j = W2[l];
  float b2s = b2v[0];
  float cb = __half2float(Cbh[n * 32 + l]);
  int off = offs[n], end = offs[n + 1];

  int p = off + g;
  for (; p + 2 < end; p += 4) {   // 2 edges per group per iter
    int2 se0 = s_se[p];
    int2 se1 = s_se[p + 2];
    float a0 = __half2float(Ah[(unsigned)se0.x * 32u + l]);
    float a1 = __half2float(Ah[(unsigned)se1.x * 32u + l]);
    const uint4* e0p = (const uint4*)(s_ea + (size_t)p * 16);
    const uint4* e1p = (const uint4*)(s_ea + (size_t)(p + 2) * 16);
    uint4 u00 = e0p[0], u01 = e0p[1];
    uint4 u10 = e1p[0], u11 = e1p[1];
    float h0 = a0 + cb, h1 = a1 + cb;
    const __half2* q00 = (const __half2*)&u00;
    const __half2* q01 = (const __half2*)&u01;
    const __half2* q10 = (const __half2*)&u10;
    const __half2* q11 = (const __half2*)&u11;
#pragma unroll
    for (int i = 0; i < 4; i++) {
      float2 f;
      f = __half22float2(q00[i]); h0 += f.x * w1e[2*i]   + f.y * w1e[2*i+1];
      f = __half22float2(q01[i]); h0 += f.x * w1e[8+2*i] + f.y * w1e[8+2*i+1];
      f = __half22float2(q10[i]); h1 += f.x * w1e[2*i]   + f.y * w1e[2*i+1];
      f = __half22float2(q11[i]); h1 += f.x * w1e[8+2*i] + f.y * w1e[8+2*i+1];
    }
    float v0 = fmaxf(h0, 0.f) * w2j;
    float v1 = fmaxf(h1, 0.f) * w2j;
    v0 = row16_reduce(v0); v1 = row16_reduce(v1);
    v0 += __shfl_xor(v0, 16); v1 += __shfl_xor(v1, 16);
    if (l == 0) {
      out[se0.y] = v0 + b2s;
      out[se1.y] = v1 + b2s;
    }
  }
  if (p < end) {
    int2 se = s_se[p];
    float a = __half2float(Ah[(unsigned)se.x * 32u + l]);
    const uint4* eap = (const uint4*)(s_ea + (size_t)p * 16);
    uint4 u0 = eap[0], u1 = eap[1];
    float hsum = a + cb;
    const __half2* hp0 = (const __half2*)&u0;
    const __half2* hp1 = (const __half2*)&u1;
#pragma unroll
    for (int i = 0; i < 4; i++) {
      float2 f0 = __half22float2(hp0[i]);
      hsum += f0.x * w1e[2 * i] + f0.y * w1e[2 * i + 1];
      float2 f1 = __half22float2(hp1[i]);
      hsum += f1.x * w1e[8 + 2 * i] + f1.y * w1e[8 + 2 * i + 1];
    }
    float hv = fmaxf(hsum, 0.f) * w2j;
    hv = row16_reduce(hv);
    hv += __shfl_xor(hv, 16);
    if (l == 0) out[se.y] = hv + b2s;
  }
}

// ---------------- launch -----------------------------------------------
extern "C" void kernel_launch(void* const* d_in, const int* in_sizes, int n_in,
                              void* d_out, int out_size, void* d_ws, size_t ws_size,
                              hipStream_t stream) {
  const float* x         = (const float*)d_in[0];
  const int*   ei        = (const int*)d_in[1];
  const float* edge_attr = (const float*)d_in[2];
  const float* Wq = (const float*)d_in[3],  *bq = (const float*)d_in[4];
  const float* Wk = (const float*)d_in[5],  *bk = (const float*)d_in[6];
  const float* Wv = (const float*)d_in[7],  *bv = (const float*)d_in[8];
  const float* We = (const float*)d_in[9];
  const float* Wskip = (const float*)d_in[10], *bskip = (const float*)d_in[11];
  const float* W1 = (const float*)d_in[12], *b1 = (const float*)d_in[13];
  const float* W2 = (const float*)d_in[14], *b2 = (const float*)d_in[15];
  float* out = (float*)d_out;

  // workspace (~70 MB); Ah/Cbh ALIAS s_tmp (dead after fine_csr)
  char* w = (char*)d_ws;
  float*   y    = (float*)w;            w += (size_t)NN * 64 * 4;   // 12.8 MB
  float*   qe   = (float*)w;            w += (size_t)NN * 64 * 4;   // 12.8 MB
  float*   u4   = (float*)w;            w += (size_t)NN * 4 * 4;    // 0.8 MB
  int2*    s_se = (int2*)w;             w += (size_t)NE * 8;        // 6.4 MB
  int2*    s_tmp = (int2*)w;            // 6.4 MB (Ah, Cbh alias inside)
  __half*  Ah   = (__half*)s_tmp;                           // 3.2 MB
  __half*  Cbh  = (__half*)((char*)s_tmp + (size_t)NN * 32 * 2); // 3.2 MB
  w += (size_t)NE * 8;
  uint4*   s_ea4 = (uint4*)w;           w += (size_t)NE * 32;       // 25.6 MB
  int*     csrpos = (int*)w;            w += (size_t)NE * 4;        // 3.2 MB
  int*     hist_all = (int*)w;          w += (size_t)NB * HB * 4;   // 627 KB
  int*     btot = (int*)w;              w += 256 * 4;
  int*     coarse_offs = (int*)w;       w += 256 * 4;
  int*     offs = (int*)w;              w += ((size_t)NN + 1) * 4;
  float*   P    = (float*)w;            w += (size_t)P_TOTAL * 4;

  precompute_kernel<<<1, 256, 0, stream>>>(Wq, Wk, bq, bk, We, P);
  node_linear_kernel<<<NODE_BLOCKS + HB, 256, 0, stream>>>(
      x, P, ei, hist_all, y, qe, u4);
  scan_buckets_kernel<<<49, 256, 0, stream>>>(hist_all, btot);
  tiny_scan_kernel<<<1, 256, 0, stream>>>(btot, coarse_offs);
  bucket_scatter_kernel<<<HB, 256, 0, stream>>>(ei, hist_all, coarse_offs,
                                                s_tmp);
  fine_csr_kernel<<<NB, 256, 0, stream>>>(s_tmp, coarse_offs, s_se, csrpos,
                                          offs);
  ea_place_kernel<<<NE / 256, 256, 0, stream>>>(edge_attr, csrpos, s_ea4);
  aggregate_kernel<<<NN / 4, 256, 0, stream>>>(y, qe, u4, x,
                                               (const __half*)s_ea4, s_se, P,
                                               We, Wv, bv, Wskip, bskip, W1, b1,
                                               offs, Ah, Cbh);
  mlp_kernel<<<NN / 4, 256, 0, stream>>>(s_se, (const __half*)s_ea4, offs,
                                         Ah, Cbh, W1, W2, b2, out);
}

// Round 19
// 227.549 us; speedup vs baseline: 1.7091x; 1.0011x over previous
//
#include <hip/hip_runtime.h>
#include <hip/hip_fp16.h>

#define NN 50000
#define NE 800000
// IN_C=16, EDGE_IN=16, HID=32, HEADS=4, HC=128
#define NB 196            // coarse buckets = ceil(NN/256)
#define HB 800            // bucket-build blocks
#define EPB 1000          // edges per bucket-build block (NE/HB)
#define NODE_BLOCKS 12500 // NN/4

// scale folded into all alpha components: log2(e)/sqrt(32)
#define SL 0.25506413f

// packed table offsets (floats)
#define PMV 0
#define MEV 1024
#define BEV 2048
#define UPV 2112
#define WPV 2176
#define WCV 2240
#define P_TOTAL 2304

// DPP-based add over lanes: quad xor1=0xB1, xor2=0x4E, row_ror:4=0x124,
// row_ror:8=0x128 (rows are 16 lanes = one head group). VALU-pipe only.
template <int CTRL>
__device__ __forceinline__ float dpp_add(float v) {
  int m = __builtin_amdgcn_update_dpp(0, __builtin_bit_cast(int, v), CTRL, 0xF, 0xF, true);
  return v + __builtin_bit_cast(float, m);
}
__device__ __forceinline__ float row16_reduce(float v) {
  v = dpp_add<0xB1>(v);
  v = dpp_add<0x4E>(v);
  v = dpp_add<0x124>(v);
  v = dpp_add<0x128>(v);
  return v;
}

// ---------------- Kernel 0: weight precompute --------------------------
__global__ __launch_bounds__(256) void precompute_kernel(
    const float* __restrict__ Wq, const float* __restrict__ Wk,
    const float* __restrict__ bq, const float* __restrict__ bk,
    const float* __restrict__ We, float* __restrict__ P) {
  int t = threadIdx.x;
  for (int idx = t; idx < 1024; idx += 256) {
    int lane = idx >> 4, i = idx & 15;
    int h = lane >> 4, tt = lane & 15;
    float am = 0.f, ae = 0.f;
#pragma unroll
    for (int c = 0; c < 32; c++) {
      float wq = Wq[i * 128 + h * 32 + c];
      am += wq * Wk[tt * 128 + h * 32 + c];
      ae += wq * We[tt * 128 + h * 32 + c];
    }
    P[PMV + idx] = am * SL;
    P[MEV + idx] = ae * SL;
  }
  if (t < 64) {
    int h = t >> 4, tt = t & 15;
    float be = 0.f, up = 0.f, wp = 0.f;
#pragma unroll
    for (int c = 0; c < 32; c++) {
      be += bq[h * 32 + c] * We[tt * 128 + h * 32 + c];
      up += Wq[tt * 128 + h * 32 + c] * bk[h * 32 + c];
      wp += bq[h * 32 + c] * Wk[tt * 128 + h * 32 + c];
    }
    P[BEV + t] = be * SL;
    P[UPV + t] = up * SL;
    P[WPV + t] = wp * SL;
  }
  if (t < 4) {
    float wc = 0.f;
#pragma unroll
    for (int c = 0; c < 32; c++) wc += bq[t * 32 + c] * bk[t * 32 + c];
    P[WCV + t] = wc * SL;
  }
}

// ---------------- Kernel 1: node precompute + coarse hist (fused) ------
__global__ __launch_bounds__(256) void node_linear_kernel(
    const float* __restrict__ x, const float* __restrict__ P,
    const int* __restrict__ ei, int* __restrict__ hist_all,
    float* __restrict__ y, float* __restrict__ qe,
    float* __restrict__ u4) {
  __shared__ int hist[NB];
  if (blockIdx.x >= NODE_BLOCKS) {
    int b = blockIdx.x - NODE_BLOCKS;  // [0, HB)
    int t = threadIdx.x;
    if (t < NB) hist[t] = 0;
    __syncthreads();
    int base = b * EPB;
    for (int i = t; i < EPB; i += 256)
      atomicAdd(&hist[ei[NE + base + i] >> 8], 1);
    __syncthreads();
    if (t < NB) hist_all[t * HB + b] = hist[t];
    return;
  }
  int wave = threadIdx.x >> 6;
  int lane = threadIdx.x & 63;
  int n = blockIdx.x * 4 + wave;
  int h = lane >> 4, t = lane & 15;

  const float4* xp = (const float4*)(x + n * 16);
  float4 X0 = xp[0], X1 = xp[1], X2 = xp[2], X3 = xp[3];
  float xr[16] = {X0.x, X0.y, X0.z, X0.w, X1.x, X1.y, X1.z, X1.w,
                  X2.x, X2.y, X2.z, X2.w, X3.x, X3.y, X3.z, X3.w};

  const float4* pm = (const float4*)(P + PMV) + lane * 4;
  const float4* me = (const float4*)(P + MEV) + lane * 4;
  float yt = 0.f, qv = P[BEV + lane];
#pragma unroll
  for (int i4 = 0; i4 < 4; i4++) {
    float4 m = pm[i4], e = me[i4];
    yt += xr[4 * i4] * m.x + xr[4 * i4 + 1] * m.y
        + xr[4 * i4 + 2] * m.z + xr[4 * i4 + 3] * m.w;
    qv += xr[4 * i4] * e.x + xr[4 * i4 + 1] * e.y
        + xr[4 * i4 + 2] * e.z + xr[4 * i4 + 3] * e.w;
  }
  y[n * 64 + lane] = yt;
  qe[n * 64 + lane] = qv;

  float pu = P[UPV + lane] * xr[t];
  pu = row16_reduce(pu);
  if (t == 0) u4[n * 4 + h] = pu;
}

// ---------------- CSR build ---------------------------------------------
__global__ __launch_bounds__(256) void scan_buckets_kernel(
    int* __restrict__ hist_all, int* __restrict__ btot) {
  int wv = blockIdx.x * 4 + (threadIdx.x >> 6);
  int l = threadIdx.x & 63;
  if (wv >= NB) return;
  int base = wv * HB;
  int run = 0;
#pragma unroll
  for (int c = 0; c < (HB + 63) / 64; c++) {
    int idx = c * 64 + l;
    int v = (idx < HB) ? hist_all[base + idx] : 0;
    int orig = v;
#pragma unroll
    for (int d = 1; d < 64; d <<= 1) {
      int u = __shfl_up(v, d);
      if (l >= d) v += u;
    }
    if (idx < HB) hist_all[base + idx] = run + v - orig;
    run += __shfl(v, 63);
  }
  if (l == 0) btot[wv] = run;
}

__global__ __launch_bounds__(256) void tiny_scan_kernel(
    const int* __restrict__ btot, int* __restrict__ coarse_offs) {
  __shared__ int sc[256];
  int t = threadIdx.x;
  int v = (t < NB) ? btot[t] : 0;
  sc[t] = v;
  __syncthreads();
  for (int d = 1; d < 256; d <<= 1) {
    int u = (t >= d) ? sc[t - d] : 0;
    __syncthreads();
    sc[t] += u;
    __syncthreads();
  }
  if (t < NB) coarse_offs[t] = sc[t] - v;
  if (t == NB - 1) coarse_offs[NB] = sc[t];
}

// scatter edge META only (8B) into coarse-bucket order
__global__ __launch_bounds__(256) void bucket_scatter_kernel(
    const int* __restrict__ ei, const int* __restrict__ cursor_all,
    const int* __restrict__ coarse_offs, int2* __restrict__ s_tmp) {
  __shared__ int cur[NB];
  int t = threadIdx.x, b = blockIdx.x;
  if (t < NB) cur[t] = cursor_all[t * HB + b] + coarse_offs[t];
  __syncthreads();
  int base = b * EPB;
  for (int i = t; i < EPB; i += 256) {
    int e = base + i;
    int src = ei[e], dst = ei[NE + e];
    int pos = atomicAdd(&cur[dst >> 8], 1);
    s_tmp[pos] = make_int2(src | ((dst & 255) << 16), e);
  }
}

// one block per bucket -> exact CSR (offs + s_se{src,eid} + csrpos[eid])
__global__ __launch_bounds__(256) void fine_csr_kernel(
    const int2* __restrict__ s_tmp, const int* __restrict__ coarse_offs,
    int2* __restrict__ s_se, int* __restrict__ csrpos,
    int* __restrict__ offs) {
  __shared__ int cnt[256], sc[256], cur[256];
  int t = threadIdx.x, b = blockIdx.x;
  int lo = coarse_offs[b], hi = coarse_offs[b + 1];
  cnt[t] = 0;
  __syncthreads();
  for (int p = lo + t; p < hi; p += 256)
    atomicAdd(&cnt[(s_tmp[p].x >> 16) & 255], 1);
  __syncthreads();
  int myc = cnt[t];
  sc[t] = myc;
  __syncthreads();
  for (int d = 1; d < 256; d <<= 1) {
    int v = (t >= d) ? sc[t - d] : 0;
    __syncthreads();
    sc[t] += v;
    __syncthreads();
  }
  int excl = sc[t] - myc;
  cur[t] = lo + excl;
  int gd = b * 256 + t;
  if (gd <= NN) offs[gd] = lo + excl;
  __syncthreads();
  for (int p = lo + t; p < hi; p += 256) {
    int2 m = s_tmp[p];
    int pos = atomicAdd(&cur[(m.x >> 16) & 255], 1);
    s_se[pos] = make_int2(m.x & 0xFFFF, m.y);
    csrpos[m.y] = pos;
  }
}

// ---------------- Kernel 2c: place edge_attr as f16 at final CSR slot --
__global__ __launch_bounds__(256) void ea_place_kernel(
    const float* __restrict__ edge_attr, const int* __restrict__ csrpos,
    uint4* __restrict__ s_ea4) {
  int e = blockIdx.x * 256 + threadIdx.x;
  const float4* eap = (const float4*)(edge_attr + (size_t)e * 16);
  float4 a = eap[0], bb = eap[1], c = eap[2], d = eap[3];
  uint4 u0, u1;
  __half2 hh;
  hh = __floats2half2_rn(a.x, a.y);   u0.x = *(unsigned*)&hh;
  hh = __floats2half2_rn(a.z, a.w);   u0.y = *(unsigned*)&hh;
  hh = __floats2half2_rn(bb.x, bb.y); u0.z = *(unsigned*)&hh;
  hh = __floats2half2_rn(bb.z, bb.w); u0.w = *(unsigned*)&hh;
  hh = __floats2half2_rn(c.x, c.y);   u1.x = *(unsigned*)&hh;
  hh = __floats2half2_rn(c.z, c.w);   u1.y = *(unsigned*)&hh;
  hh = __floats2half2_rn(d.x, d.y);   u1.z = *(unsigned*)&hh;
  hh = __floats2half2_rn(d.z, d.w);   u1.w = *(unsigned*)&hh;
  int pos = csrpos[e];
  s_ea4[(size_t)pos * 2]     = u0;
  s_ea4[(size_t)pos * 2 + 1] = u1;
}

// ---------------- Kernel 3: aggregation + A/C epilogue -----------------
// one wave per dst node; 16 lanes/head; sequential s_se/s_ea; 8-edge ILP
// with MASKED 8-wide tail (no serial per-edge path); DPP dot reduce;
// w4 folded into dot; LDS-broadcast epilogue.
__global__ __launch_bounds__(256) void aggregate_kernel(
    const float* __restrict__ y, const float* __restrict__ qe,
    const float* __restrict__ u4,
    const float* __restrict__ x, const __half* __restrict__ s_ea,
    const int2* __restrict__ s_se, const float* __restrict__ P,
    const float* __restrict__ We, const float* __restrict__ Wv,
    const float* __restrict__ bv,
    const float* __restrict__ Wskip, const float* __restrict__ bskip,
    const float* __restrict__ W1, const float* __restrict__ b1,
    const int* __restrict__ offs,
    __half* __restrict__ Ah, __half* __restrict__ Cbh) {
  __shared__ float red[4][128];
  int wave = threadIdx.x >> 6, lane = threadIdx.x & 63;
  int n = blockIdx.x * 4 + wave;
  int h = lane >> 4, t = lane & 15;
  int base = h * 32 + t;

  float yt2 = y[n * 64 + lane] + P[WPV + lane];   // fold bq.k term
  float qet = qe[n * 64 + lane];
  float un_wc = u4[n * 4 + h] + P[WCV + h];       // per-node constant
  int off = offs[n], end = offs[n + 1];

  float s = 0.f, ax = 0.f, ae = 0.f;
  int j = off;
  for (; j + 8 <= end; j += 8) {
    const uint4* sp = (const uint4*)&s_se[j];
    uint4 sa = sp[0], sb = sp[1], sc4 = sp[2], sd = sp[3];
    int src[8] = {(int)sa.x, (int)sa.z, (int)sb.x, (int)sb.z,
                  (int)sc4.x, (int)sc4.z, (int)sd.x, (int)sd.z};
    float xs[8], ea[8];
#pragma unroll
    for (int u = 0; u < 8; u++) {
      xs[u] = x[(unsigned)src[u] * 16u + (unsigned)t];
      ea[u] = __half2float(s_ea[(size_t)(j + u) * 16 + t]);
    }
    float p[8];
#pragma unroll
    for (int u = 0; u < 8; u++) p[u] = fmaf(yt2, xs[u], qet * ea[u]);
#pragma unroll
    for (int u = 0; u < 8; u++) p[u] = row16_reduce(p[u]);
#pragma unroll
    for (int u = 0; u < 8; u++) {
      float wgt = exp2f(p[u] + un_wc);
      s += wgt;
      ax = fmaf(wgt, xs[u], ax);
      ae = fmaf(wgt, ea[u], ae);
    }
  }
  if (j < end) {  // masked 8-wide tail (1..7 edges), same ILP as body
    int src[8], jd[8];
    float xs[8], ea[8];
#pragma unroll
    for (int u = 0; u < 8; u++) {
      jd[u] = (j + u < end) ? (j + u) : (end - 1);
      src[u] = s_se[jd[u]].x;
    }
#pragma unroll
    for (int u = 0; u < 8; u++) {
      xs[u] = x[(unsigned)src[u] * 16u + (unsigned)t];
      ea[u] = __half2float(s_ea[(size_t)jd[u] * 16 + t]);
    }
    float p[8];
#pragma unroll
    for (int u = 0; u < 8; u++) p[u] = fmaf(yt2, xs[u], qet * ea[u]);
#pragma unroll
    for (int u = 0; u < 8; u++) p[u] = row16_reduce(p[u]);
#pragma unroll
    for (int u = 0; u < 8; u++) {
      float wgt = (j + u < end) ? exp2f(p[u] + un_wc) : 0.f;
      s += wgt;
      ax = fmaf(wgt, xs[u], ax);
      ae = fmaf(wgt, ea[u], ae);
    }
  }

  float inv = (end > off) ? 1.f / s : 0.f;
  float dflag = (end > off) ? 1.f : 0.f;
  float* rw = red[wave];
  rw[lane] = ax * inv;        // axn
  rw[64 + lane] = ae * inv;   // aen

  float r0 = dflag * bv[base], r1 = dflag * bv[base + 16];
  const float4* axp = (const float4*)&rw[h * 16];
  const float4* aep = (const float4*)&rw[64 + h * 16];
#pragma unroll
  for (int k = 0; k < 4; k++) {
    float4 a4 = axp[k], e4 = aep[k];
    int i0 = 4 * k;
    r0 += a4.x * Wv[(i0    ) * 128 + base] + e4.x * We[(i0    ) * 128 + base];
    r0 += a4.y * Wv[(i0 + 1) * 128 + base] + e4.y * We[(i0 + 1) * 128 + base];
    r0 += a4.z * Wv[(i0 + 2) * 128 + base] + e4.z * We[(i0 + 2) * 128 + base];
    r0 += a4.w * Wv[(i0 + 3) * 128 + base] + e4.w * We[(i0 + 3) * 128 + base];
    r1 += a4.x * Wv[(i0    ) * 128 + base + 16] + e4.x * We[(i0    ) * 128 + base + 16];
    r1 += a4.y * Wv[(i0 + 1) * 128 + base + 16] + e4.y * We[(i0 + 1) * 128 + base + 16];
    r1 += a4.z * Wv[(i0 + 2) * 128 + base + 16] + e4.z * We[(i0 + 2) * 128 + base + 16];
    r1 += a4.w * Wv[(i0 + 3) * 128 + base + 16] + e4.w * We[(i0 + 3) * 128 + base + 16];
  }
  // mean over heads
  r0 += __shfl_xor(r0, 16); r0 += __shfl_xor(r0, 32);
  r1 += __shfl_xor(r1, 16); r1 += __shfl_xor(r1, 32);

  // skip connection
  float sk0 = bskip[t], sk1 = bskip[t + 16];
#pragma unroll
  for (int i = 0; i < 16; i++) {
    float xi = x[n * 16 + i];
    sk0 += xi * Wskip[i * 32 + t];
    sk1 += xi * Wskip[i * 32 + t + 16];
  }
  float o0 = 0.25f * r0 + sk0;  // out[n][t]
  float o1 = 0.25f * r1 + sk1;  // out[n][t+16]

  // broadcast o0/o1 via LDS (axn/aen dead now; reuse rw[0..31])
  if (lane < 16) {
    rw[t] = o0;
    rw[16 + t] = o1;
  }

  // A[n][jj] = out@W1[0:32]; Cb[n][jj] = out@W1[48:80] + b1  (stored f16)
  int jj = lane & 31;
  int roff = (lane < 32) ? 0 : 48;
  float acc = (lane < 32) ? 0.f : b1[jj];
  const float4* op = (const float4*)rw;
#pragma unroll
  for (int k = 0; k < 4; k++) {
    float4 o4 = op[k];        // o0[4k..4k+3]
    int r = roff + 4 * k;
    acc += o4.x * W1[(r    ) * 32 + jj] + o4.y * W1[(r + 1) * 32 + jj]
         + o4.z * W1[(r + 2) * 32 + jj] + o4.w * W1[(r + 3) * 32 + jj];
  }
#pragma unroll
  for (int k = 0; k < 4; k++) {
    float4 o4 = op[4 + k];    // o1[4k..4k+3] -> rows roff+16+
    int r = roff + 16 + 4 * k;
    acc += o4.x * W1[(r    ) * 32 + jj] + o4.y * W1[(r + 1) * 32 + jj]
         + o4.z * W1[(r + 2) * 32 + jj] + o4.w * W1[(r + 3) * 32 + jj];
  }
  float nb = __shfl_xor(acc, 1);
  if ((lane & 1) == 0) {
    __half2 hh = __floats2half2_rn(acc, nb);
    if (lane < 32) *(__half2*)(Ah  + n * 32 + jj) = hh;
    else           *(__half2*)(Cbh + n * 32 + jj) = hh;
  }
}

// ---------------- Kernel 4: per-edge MLP, CSR order, 2-edge ILP --------
__global__ __launch_bounds__(256) void mlp_kernel(
    const int2* __restrict__ s_se, const __half* __restrict__ s_ea,
    const int* __restrict__ offs,
    const __half* __restrict__ Ah, const __half* __restrict__ Cbh,
    const float* __restrict__ W1, const float* __restrict__ W2,
    const float* __restrict__ b2v, float* __restrict__ out) {
  int wave = threadIdx.x >> 6, lane = threadIdx.x & 63;
  int n = blockIdx.x * 4 + wave;
  int g = lane >> 5, l = lane & 31;

  float w1e[16];
#pragma unroll
  for (int i = 0; i < 16; i++) w1e[i] = W1[(32 + i) * 32 + l];
  float w2j = W2[l];
  float b2s = b2v[0];
  float cb = __half2float(Cbh[n * 32 + l]);
  int off = offs[n], end = offs[n + 1];

  int p = off + g;
  for (; p + 2 < end; p += 4) {   // 2 edges per group per iter
    int2 se0 = s_se[p];
    int2 se1 = s_se[p + 2];
    float a0 = __half2float(Ah[(unsigned)se0.x * 32u + l]);
    float a1 = __half2float(Ah[(unsigned)se1.x * 32u + l]);
    const uint4* e0p = (const uint4*)(s_ea + (size_t)p * 16);
    const uint4* e1p = (const uint4*)(s_ea + (size_t)(p + 2) * 16);
    uint4 u00 = e0p[0], u01 = e0p[1];
    uint4 u10 = e1p[0], u11 = e1p[1];
    float h0 = a0 + cb, h1 = a1 + cb;
    const __half2* q00 = (const __half2*)&u00;
    const __half2* q01 = (const __half2*)&u01;
    const __half2* q10 = (const __half2*)&u10;
    const __half2* q11 = (const __half2*)&u11;
#pragma unroll
    for (int i = 0; i < 4; i++) {
      float2 f;
      f = __half22float2(q00[i]); h0 += f.x * w1e[2*i]   + f.y * w1e[2*i+1];
      f = __half22float2(q01[i]); h0 += f.x * w1e[8+2*i] + f.y * w1e[8+2*i+1];
      f = __half22float2(q10[i]); h1 += f.x * w1e[2*i]   + f.y * w1e[2*i+1];
      f = __half22float2(q11[i]); h1 += f.x * w1e[8+2*i] + f.y * w1e[8+2*i+1];
    }
    float v0 = fmaxf(h0, 0.f) * w2j;
    float v1 = fmaxf(h1, 0.f) * w2j;
    v0 = row16_reduce(v0); v1 = row16_reduce(v1);
    v0 += __shfl_xor(v0, 16); v1 += __shfl_xor(v1, 16);
    if (l == 0) {
      out[se0.y] = v0 + b2s;
      out[se1.y] = v1 + b2s;
    }
  }
  if (p < end) {
    int2 se = s_se[p];
    float a = __half2float(Ah[(unsigned)se.x * 32u + l]);
    const uint4* eap = (const uint4*)(s_ea + (size_t)p * 16);
    uint4 u0 = eap[0], u1 = eap[1];
    float hsum = a + cb;
    const __half2* hp0 = (const __half2*)&u0;
    const __half2* hp1 = (const __half2*)&u1;
#pragma unroll
    for (int i = 0; i < 4; i++) {
      float2 f0 = __half22float2(hp0[i]);
      hsum += f0.x * w1e[2 * i] + f0.y * w1e[2 * i + 1];
      float2 f1 = __half22float2(hp1[i]);
      hsum += f1.x * w1e[8 + 2 * i] + f1.y * w1e[8 + 2 * i + 1];
    }
    float hv = fmaxf(hsum, 0.f) * w2j;
    hv = row16_reduce(hv);
    hv += __shfl_xor(hv, 16);
    if (l == 0) out[se.y] = hv + b2s;
  }
}

// ---------------- launch -----------------------------------------------
extern "C" void kernel_launch(void* const* d_in, const int* in_sizes, int n_in,
                              void* d_out, int out_size, void* d_ws, size_t ws_size,
                              hipStream_t stream) {
  const float* x         = (const float*)d_in[0];
  const int*   ei        = (const int*)d_in[1];
  const float* edge_attr = (const float*)d_in[2];
  const float* Wq = (const float*)d_in[3],  *bq = (const float*)d_in[4];
  const float* Wk = (const float*)d_in[5],  *bk = (const float*)d_in[6];
  const float* Wv = (const float*)d_in[7],  *bv = (const float*)d_in[8];
  const float* We = (const float*)d_in[9];
  const float* Wskip = (const float*)d_in[10], *bskip = (const float*)d_in[11];
  const float* W1 = (const float*)d_in[12], *b1 = (const float*)d_in[13];
  const float* W2 = (const float*)d_in[14], *b2 = (const float*)d_in[15];
  float* out = (float*)d_out;

  // workspace (~70 MB); Ah/Cbh ALIAS s_tmp (dead after fine_csr)
  char* w = (char*)d_ws;
  float*   y    = (float*)w;            w += (size_t)NN * 64 * 4;   // 12.8 MB
  float*   qe   = (float*)w;            w += (size_t)NN * 64 * 4;   // 12.8 MB
  float*   u4   = (float*)w;            w += (size_t)NN * 4 * 4;    // 0.8 MB
  int2*    s_se = (int2*)w;             w += (size_t)NE * 8;        // 6.4 MB
  int2*    s_tmp = (int2*)w;            // 6.4 MB (Ah, Cbh alias inside)
  __half*  Ah   = (__half*)s_tmp;                           // 3.2 MB
  __half*  Cbh  = (__half*)((char*)s_tmp + (size_t)NN * 32 * 2); // 3.2 MB
  w += (size_t)NE * 8;
  uint4*   s_ea4 = (uint4*)w;           w += (size_t)NE * 32;       // 25.6 MB
  int*     csrpos = (int*)w;            w += (size_t)NE * 4;        // 3.2 MB
  int*     hist_all = (int*)w;          w += (size_t)NB * HB * 4;   // 627 KB
  int*     btot = (int*)w;              w += 256 * 4;
  int*     coarse_offs = (int*)w;       w += 256 * 4;
  int*     offs = (int*)w;              w += ((size_t)NN + 1) * 4;
  float*   P    = (float*)w;            w += (size_t)P_TOTAL * 4;

  precompute_kernel<<<1, 256, 0, stream>>>(Wq, Wk, bq, bk, We, P);
  node_linear_kernel<<<NODE_BLOCKS + HB, 256, 0, stream>>>(
      x, P, ei, hist_all, y, qe, u4);
  scan_buckets_kernel<<<49, 256, 0, stream>>>(hist_all, btot);
  tiny_scan_kernel<<<1, 256, 0, stream>>>(btot, coarse_offs);
  bucket_scatter_kernel<<<HB, 256, 0, stream>>>(ei, hist_all, coarse_offs,
                                                s_tmp);
  fine_csr_kernel<<<NB, 256, 0, stream>>>(s_tmp, coarse_offs, s_se, csrpos,
                                          offs);
  ea_place_kernel<<<NE / 256, 256, 0, stream>>>(edge_attr, csrpos, s_ea4);
  aggregate_kernel<<<NN / 4, 256, 0, stream>>>(y, qe, u4, x,
                                               (const __half*)s_ea4, s_se, P,
                                               We, Wv, bv, Wskip, bskip, W1, b1,
                                               offs, Ah, Cbh);
  mlp_kernel<<<NN / 4, 256, 0, stream>>>(s_se, (const __half*)s_ea4, offs,
                                         Ah, Cbh, W1, W2, b2, out);
}

// Round 20
// 225.921 us; speedup vs baseline: 1.7214x; 1.0072x over previous
//
#include <hip/hip_runtime.h>
#include <hip/hip_fp16.h>

#define NN 50000
#define NE 800000
// IN_C=16, EDGE_IN=16, HID=32, HEADS=4, HC=128
#define NB 196            // coarse buckets = ceil(NN/256)
#define HB 800            // bucket-build blocks
#define EPB 1000          // edges per bucket-build block (NE/HB)
#define NODE_BLOCKS 12500 // NN/4

// scale folded into all alpha components: log2(e)/sqrt(32)
#define SL 0.25506413f

// packed table offsets (floats)
#define PMV 0
#define MEV 1024
#define BEV 2048
#define UPV 2112
#define WPV 2176
#define WCV 2240
#define P_TOTAL 2304

// DPP-based add over lanes: quad xor1=0xB1, xor2=0x4E, row_ror:4=0x124,
// row_ror:8=0x128 (rows are 16 lanes = one head group). VALU-pipe only.
template <int CTRL>
__device__ __forceinline__ float dpp_add(float v) {
  int m = __builtin_amdgcn_update_dpp(0, __builtin_bit_cast(int, v), CTRL, 0xF, 0xF, true);
  return v + __builtin_bit_cast(float, m);
}
__device__ __forceinline__ float row16_reduce(float v) {
  v = dpp_add<0xB1>(v);
  v = dpp_add<0x4E>(v);
  v = dpp_add<0x124>(v);
  v = dpp_add<0x128>(v);
  return v;
}

// ---------------- Kernel 0: weight precompute --------------------------
__global__ __launch_bounds__(256) void precompute_kernel(
    const float* __restrict__ Wq, const float* __restrict__ Wk,
    const float* __restrict__ bq, const float* __restrict__ bk,
    const float* __restrict__ We, float* __restrict__ P) {
  int t = threadIdx.x;
  for (int idx = t; idx < 1024; idx += 256) {
    int lane = idx >> 4, i = idx & 15;
    int h = lane >> 4, tt = lane & 15;
    float am = 0.f, ae = 0.f;
#pragma unroll
    for (int c = 0; c < 32; c++) {
      float wq = Wq[i * 128 + h * 32 + c];
      am += wq * Wk[tt * 128 + h * 32 + c];
      ae += wq * We[tt * 128 + h * 32 + c];
    }
    P[PMV + idx] = am * SL;
    P[MEV + idx] = ae * SL;
  }
  if (t < 64) {
    int h = t >> 4, tt = t & 15;
    float be = 0.f, up = 0.f, wp = 0.f;
#pragma unroll
    for (int c = 0; c < 32; c++) {
      be += bq[h * 32 + c] * We[tt * 128 + h * 32 + c];
      up += Wq[tt * 128 + h * 32 + c] * bk[h * 32 + c];
      wp += bq[h * 32 + c] * Wk[tt * 128 + h * 32 + c];
    }
    P[BEV + t] = be * SL;
    P[UPV + t] = up * SL;
    P[WPV + t] = wp * SL;
  }
  if (t < 4) {
    float wc = 0.f;
#pragma unroll
    for (int c = 0; c < 32; c++) wc += bq[t * 32 + c] * bk[t * 32 + c];
    P[WCV + t] = wc * SL;
  }
}

// ---------------- Kernel 1: node precompute + coarse hist (fused) ------
__global__ __launch_bounds__(256) void node_linear_kernel(
    const float* __restrict__ x, const float* __restrict__ P,
    const int* __restrict__ ei, int* __restrict__ hist_all,
    float* __restrict__ y, float* __restrict__ qe,
    float* __restrict__ u4) {
  __shared__ int hist[NB];
  if (blockIdx.x >= NODE_BLOCKS) {
    int b = blockIdx.x - NODE_BLOCKS;  // [0, HB)
    int t = threadIdx.x;
    if (t < NB) hist[t] = 0;
    __syncthreads();
    int base = b * EPB;
    for (int i = t; i < EPB; i += 256)
      atomicAdd(&hist[ei[NE + base + i] >> 8], 1);
    __syncthreads();
    if (t < NB) hist_all[t * HB + b] = hist[t];
    return;
  }
  int wave = threadIdx.x >> 6;
  int lane = threadIdx.x & 63;
  int n = blockIdx.x * 4 + wave;
  int h = lane >> 4, t = lane & 15;

  const float4* xp = (const float4*)(x + n * 16);
  float4 X0 = xp[0], X1 = xp[1], X2 = xp[2], X3 = xp[3];
  float xr[16] = {X0.x, X0.y, X0.z, X0.w, X1.x, X1.y, X1.z, X1.w,
                  X2.x, X2.y, X2.z, X2.w, X3.x, X3.y, X3.z, X3.w};

  const float4* pm = (const float4*)(P + PMV) + lane * 4;
  const float4* me = (const float4*)(P + MEV) + lane * 4;
  float yt = 0.f, qv = P[BEV + lane];
#pragma unroll
  for (int i4 = 0; i4 < 4; i4++) {
    float4 m = pm[i4], e = me[i4];
    yt += xr[4 * i4] * m.x + xr[4 * i4 + 1] * m.y
        + xr[4 * i4 + 2] * m.z + xr[4 * i4 + 3] * m.w;
    qv += xr[4 * i4] * e.x + xr[4 * i4 + 1] * e.y
        + xr[4 * i4 + 2] * e.z + xr[4 * i4 + 3] * e.w;
  }
  y[n * 64 + lane] = yt;
  qe[n * 64 + lane] = qv;

  float pu = P[UPV + lane] * xr[t];
  pu = row16_reduce(pu);
  if (t == 0) u4[n * 4 + h] = pu;
}

// ---------------- CSR build ---------------------------------------------
__global__ __launch_bounds__(256) void scan_buckets_kernel(
    int* __restrict__ hist_all, int* __restrict__ btot) {
  int wv = blockIdx.x * 4 + (threadIdx.x >> 6);
  int l = threadIdx.x & 63;
  if (wv >= NB) return;
  int base = wv * HB;
  int run = 0;
#pragma unroll
  for (int c = 0; c < (HB + 63) / 64; c++) {
    int idx = c * 64 + l;
    int v = (idx < HB) ? hist_all[base + idx] : 0;
    int orig = v;
#pragma unroll
    for (int d = 1; d < 64; d <<= 1) {
      int u = __shfl_up(v, d);
      if (l >= d) v += u;
    }
    if (idx < HB) hist_all[base + idx] = run + v - orig;
    run += __shfl(v, 63);
  }
  if (l == 0) btot[wv] = run;
}

__global__ __launch_bounds__(256) void tiny_scan_kernel(
    const int* __restrict__ btot, int* __restrict__ coarse_offs) {
  __shared__ int sc[256];
  int t = threadIdx.x;
  int v = (t < NB) ? btot[t] : 0;
  sc[t] = v;
  __syncthreads();
  for (int d = 1; d < 256; d <<= 1) {
    int u = (t >= d) ? sc[t - d] : 0;
    __syncthreads();
    sc[t] += u;
    __syncthreads();
  }
  if (t < NB) coarse_offs[t] = sc[t] - v;
  if (t == NB - 1) coarse_offs[NB] = sc[t];
}

// scatter edge META only (8B) into coarse-bucket order
__global__ __launch_bounds__(256) void bucket_scatter_kernel(
    const int* __restrict__ ei, const int* __restrict__ cursor_all,
    const int* __restrict__ coarse_offs, int2* __restrict__ s_tmp) {
  __shared__ int cur[NB];
  int t = threadIdx.x, b = blockIdx.x;
  if (t < NB) cur[t] = cursor_all[t * HB + b] + coarse_offs[t];
  __syncthreads();
  int base = b * EPB;
  for (int i = t; i < EPB; i += 256) {
    int e = base + i;
    int src = ei[e], dst = ei[NE + e];
    int pos = atomicAdd(&cur[dst >> 8], 1);
    s_tmp[pos] = make_int2(src | ((dst & 255) << 16), e);
  }
}

// one block per bucket -> exact CSR (offs + s_se{src,eid})
__global__ __launch_bounds__(256) void fine_csr_kernel(
    const int2* __restrict__ s_tmp, const int* __restrict__ coarse_offs,
    int2* __restrict__ s_se, int* __restrict__ offs) {
  __shared__ int cnt[256], sc[256], cur[256];
  int t = threadIdx.x, b = blockIdx.x;
  int lo = coarse_offs[b], hi = coarse_offs[b + 1];
  cnt[t] = 0;
  __syncthreads();
  for (int p = lo + t; p < hi; p += 256)
    atomicAdd(&cnt[(s_tmp[p].x >> 16) & 255], 1);
  __syncthreads();
  int myc = cnt[t];
  sc[t] = myc;
  __syncthreads();
  for (int d = 1; d < 256; d <<= 1) {
    int v = (t >= d) ? sc[t - d] : 0;
    __syncthreads();
    sc[t] += v;
    __syncthreads();
  }
  int excl = sc[t] - myc;
  cur[t] = lo + excl;
  int gd = b * 256 + t;
  if (gd <= NN) offs[gd] = lo + excl;
  __syncthreads();
  for (int p = lo + t; p < hi; p += 256) {
    int2 m = s_tmp[p];
    int pos = atomicAdd(&cur[(m.x >> 16) & 255], 1);
    s_se[pos] = make_int2(m.x & 0xFFFF, m.y);
  }
}

// ---------------- Kernel 2c: build s_ea in CSR order (inverted) --------
// sequential s_se read + SEQUENTIAL full-line s_ea writes; the edge_attr
// read is a random 64B gather (L2/L3-served, no RMW penalty).
__global__ __launch_bounds__(256) void ea_place_kernel(
    const float* __restrict__ edge_attr, const int2* __restrict__ s_se,
    uint4* __restrict__ s_ea4) {
  int pos = blockIdx.x * 256 + threadIdx.x;
  int eid = s_se[pos].y;
  const float4* eap = (const float4*)(edge_attr + (size_t)eid * 16);
  float4 a = eap[0], bb = eap[1], c = eap[2], d = eap[3];
  uint4 u0, u1;
  __half2 hh;
  hh = __floats2half2_rn(a.x, a.y);   u0.x = *(unsigned*)&hh;
  hh = __floats2half2_rn(a.z, a.w);   u0.y = *(unsigned*)&hh;
  hh = __floats2half2_rn(bb.x, bb.y); u0.z = *(unsigned*)&hh;
  hh = __floats2half2_rn(bb.z, bb.w); u0.w = *(unsigned*)&hh;
  hh = __floats2half2_rn(c.x, c.y);   u1.x = *(unsigned*)&hh;
  hh = __floats2half2_rn(c.z, c.w);   u1.y = *(unsigned*)&hh;
  hh = __floats2half2_rn(d.x, d.y);   u1.z = *(unsigned*)&hh;
  hh = __floats2half2_rn(d.z, d.w);   u1.w = *(unsigned*)&hh;
  s_ea4[(size_t)pos * 2]     = u0;
  s_ea4[(size_t)pos * 2 + 1] = u1;
}

// ---------------- Kernel 3: aggregation + A/C epilogue -----------------
// one wave per dst node; 16 lanes/head; sequential s_se/s_ea; 8-edge ILP
// + serial tail; DPP dot reduce; w4 folded into dot; LDS-broadcast
// epilogue.
__global__ __launch_bounds__(256) void aggregate_kernel(
    const float* __restrict__ y, const float* __restrict__ qe,
    const float* __restrict__ u4,
    const float* __restrict__ x, const __half* __restrict__ s_ea,
    const int2* __restrict__ s_se, const float* __restrict__ P,
    const float* __restrict__ We, const float* __restrict__ Wv,
    const float* __restrict__ bv,
    const float* __restrict__ Wskip, const float* __restrict__ bskip,
    const float* __restrict__ W1, const float* __restrict__ b1,
    const int* __restrict__ offs,
    __half* __restrict__ Ah, __half* __restrict__ Cbh) {
  __shared__ float red[4][128];
  int wave = threadIdx.x >> 6, lane = threadIdx.x & 63;
  int n = blockIdx.x * 4 + wave;
  int h = lane >> 4, t = lane & 15;
  int base = h * 32 + t;

  float yt2 = y[n * 64 + lane] + P[WPV + lane];   // fold bq.k term
  float qet = qe[n * 64 + lane];
  float un_wc = u4[n * 4 + h] + P[WCV + h];       // per-node constant
  int off = offs[n], end = offs[n + 1];

  float s = 0.f, ax = 0.f, ae = 0.f;
  int j = off;
  for (; j + 8 <= end; j += 8) {
    const uint4* sp = (const uint4*)&s_se[j];
    uint4 sa = sp[0], sb = sp[1], sc4 = sp[2], sd = sp[3];
    int src[8] = {(int)sa.x, (int)sa.z, (int)sb.x, (int)sb.z,
                  (int)sc4.x, (int)sc4.z, (int)sd.x, (int)sd.z};
    float xs[8], ea[8];
#pragma unroll
    for (int u = 0; u < 8; u++) {
      xs[u] = x[(unsigned)src[u] * 16u + (unsigned)t];
      ea[u] = __half2float(s_ea[(size_t)(j + u) * 16 + t]);
    }
    float p[8];
#pragma unroll
    for (int u = 0; u < 8; u++) p[u] = fmaf(yt2, xs[u], qet * ea[u]);
#pragma unroll
    for (int u = 0; u < 8; u++) p[u] = row16_reduce(p[u]);
#pragma unroll
    for (int u = 0; u < 8; u++) {
      float wgt = exp2f(p[u] + un_wc);
      s += wgt;
      ax = fmaf(wgt, xs[u], ax);
      ae = fmaf(wgt, ea[u], ae);
    }
  }
  for (; j < end; j++) {
    int srcu = s_se[j].x;
    float xs = x[(unsigned)srcu * 16u + (unsigned)t];
    float ea_ = __half2float(s_ea[(size_t)j * 16 + t]);
    float p = fmaf(yt2, xs, qet * ea_);
    p = row16_reduce(p);
    float wgt = exp2f(p + un_wc);
    s += wgt;
    ax = fmaf(wgt, xs, ax);
    ae = fmaf(wgt, ea_, ae);
  }

  float inv = (end > off) ? 1.f / s : 0.f;
  float dflag = (end > off) ? 1.f : 0.f;
  float* rw = red[wave];
  rw[lane] = ax * inv;        // axn
  rw[64 + lane] = ae * inv;   // aen

  float r0 = dflag * bv[base], r1 = dflag * bv[base + 16];
  const float4* axp = (const float4*)&rw[h * 16];
  const float4* aep = (const float4*)&rw[64 + h * 16];
#pragma unroll
  for (int k = 0; k < 4; k++) {
    float4 a4 = axp[k], e4 = aep[k];
    int i0 = 4 * k;
    r0 += a4.x * Wv[(i0    ) * 128 + base] + e4.x * We[(i0    ) * 128 + base];
    r0 += a4.y * Wv[(i0 + 1) * 128 + base] + e4.y * We[(i0 + 1) * 128 + base];
    r0 += a4.z * Wv[(i0 + 2) * 128 + base] + e4.z * We[(i0 + 2) * 128 + base];
    r0 += a4.w * Wv[(i0 + 3) * 128 + base] + e4.w * We[(i0 + 3) * 128 + base];
    r1 += a4.x * Wv[(i0    ) * 128 + base + 16] + e4.x * We[(i0    ) * 128 + base + 16];
    r1 += a4.y * Wv[(i0 + 1) * 128 + base + 16] + e4.y * We[(i0 + 1) * 128 + base + 16];
    r1 += a4.z * Wv[(i0 + 2) * 128 + base + 16] + e4.z * We[(i0 + 2) * 128 + base + 16];
    r1 += a4.w * Wv[(i0 + 3) * 128 + base + 16] + e4.w * We[(i0 + 3) * 128 + base + 16];
  }
  // mean over heads
  r0 += __shfl_xor(r0, 16); r0 += __shfl_xor(r0, 32);
  r1 += __shfl_xor(r1, 16); r1 += __shfl_xor(r1, 32);

  // skip connection
  float sk0 = bskip[t], sk1 = bskip[t + 16];
#pragma unroll
  for (int i = 0; i < 16; i++) {
    float xi = x[n * 16 + i];
    sk0 += xi * Wskip[i * 32 + t];
    sk1 += xi * Wskip[i * 32 + t + 16];
  }
  float o0 = 0.25f * r0 + sk0;  // out[n][t]
  float o1 = 0.25f * r1 + sk1;  // out[n][t+16]

  // broadcast o0/o1 via LDS (axn/aen dead now; reuse rw[0..31])
  if (lane < 16) {
    rw[t] = o0;
    rw[16 + t] = o1;
  }

  // A[n][jj] = out@W1[0:32]; Cb[n][jj] = out@W1[48:80] + b1  (stored f16)
  int jj = lane & 31;
  int roff = (lane < 32) ? 0 : 48;
  float acc = (lane < 32) ? 0.f : b1[jj];
  const float4* op = (const float4*)rw;
#pragma unroll
  for (int k = 0; k < 4; k++) {
    float4 o4 = op[k];        // o0[4k..4k+3]
    int r = roff + 4 * k;
    acc += o4.x * W1[(r    ) * 32 + jj] + o4.y * W1[(r + 1) * 32 + jj]
         + o4.z * W1[(r + 2) * 32 + jj] + o4.w * W1[(r + 3) * 32 + jj];
  }
#pragma unroll
  for (int k = 0; k < 4; k++) {
    float4 o4 = op[4 + k];    // o1[4k..4k+3] -> rows roff+16+
    int r = roff + 16 + 4 * k;
    acc += o4.x * W1[(r    ) * 32 + jj] + o4.y * W1[(r + 1) * 32 + jj]
         + o4.z * W1[(r + 2) * 32 + jj] + o4.w * W1[(r + 3) * 32 + jj];
  }
  float nb = __shfl_xor(acc, 1);
  if ((lane & 1) == 0) {
    __half2 hh = __floats2half2_rn(acc, nb);
    if (lane < 32) *(__half2*)(Ah  + n * 32 + jj) = hh;
    else           *(__half2*)(Cbh + n * 32 + jj) = hh;
  }
}

// ---------------- Kernel 4: per-edge MLP, CSR order, 2-edge ILP --------
__global__ __launch_bounds__(256) void mlp_kernel(
    const int2* __restrict__ s_se, const __half* __restrict__ s_ea,
    const int* __restrict__ offs,
    const __half* __restrict__ Ah, const __half* __restrict__ Cbh,
    const float* __restrict__ W1, const float* __restrict__ W2,
    const float* __restrict__ b2v, float* __restrict__ out) {
  int wave = threadIdx.x >> 6, lane = threadIdx.x & 63;
  int n = blockIdx.x * 4 + wave;
  int g = lane >> 5, l = lane & 31;

  float w1e[16];
#pragma unroll
  for (int i = 0; i < 16; i++) w1e[i] = W1[(32 + i) * 32 + l];
  float w2j = W2[l];
  float b2s = b2v[0];
  float cb = __half2float(Cbh[n * 32 + l]);
  int off = offs[n], end = offs[n + 1];

  int p = off + g;
  for (; p + 2 < end; p += 4) {   // 2 edges per group per iter
    int2 se0 = s_se[p];
    int2 se1 = s_se[p + 2];
    float a0 = __half2float(Ah[(unsigned)se0.x * 32u + l]);
    float a1 = __half2float(Ah[(unsigned)se1.x * 32u + l]);
    const uint4* e0p = (const uint4*)(s_ea + (size_t)p * 16);
    const uint4* e1p = (const uint4*)(s_ea + (size_t)(p + 2) * 16);
    uint4 u00 = e0p[0], u01 = e0p[1];
    uint4 u10 = e1p[0], u11 = e1p[1];
    float h0 = a0 + cb, h1 = a1 + cb;
    const __half2* q00 = (const __half2*)&u00;
    const __half2* q01 = (const __half2*)&u01;
    const __half2* q10 = (const __half2*)&u10;
    const __half2* q11 = (const __half2*)&u11;
#pragma unroll
    for (int i = 0; i < 4; i++) {
      float2 f;
      f = __half22float2(q00[i]); h0 += f.x * w1e[2*i]   + f.y * w1e[2*i+1];
      f = __half22float2(q01[i]); h0 += f.x * w1e[8+2*i] + f.y * w1e[8+2*i+1];
      f = __half22float2(q10[i]); h1 += f.x * w1e[2*i]   + f.y * w1e[2*i+1];
      f = __half22float2(q11[i]); h1 += f.x * w1e[8+2*i] + f.y * w1e[8+2*i+1];
    }
    float v0 = fmaxf(h0, 0.f) * w2j;
    float v1 = fmaxf(h1, 0.f) * w2j;
    v0 = row16_reduce(v0); v1 = row16_reduce(v1);
    v0 += __shfl_xor(v0, 16); v1 += __shfl_xor(v1, 16);
    if (l == 0) {
      out[se0.y] = v0 + b2s;
      out[se1.y] = v1 + b2s;
    }
  }
  if (p < end) {
    int2 se = s_se[p];
    float a = __half2float(Ah[(unsigned)se.x * 32u + l]);
    const uint4* eap = (const uint4*)(s_ea + (size_t)p * 16);
    uint4 u0 = eap[0], u1 = eap[1];
    float hsum = a + cb;
    const __half2* hp0 = (const __half2*)&u0;
    const __half2* hp1 = (const __half2*)&u1;
#pragma unroll
    for (int i = 0; i < 4; i++) {
      float2 f0 = __half22float2(hp0[i]);
      hsum += f0.x * w1e[2 * i] + f0.y * w1e[2 * i + 1];
      float2 f1 = __half22float2(hp1[i]);
      hsum += f1.x * w1e[8 + 2 * i] + f1.y * w1e[8 + 2 * i + 1];
    }
    float hv = fmaxf(hsum, 0.f) * w2j;
    hv = row16_reduce(hv);
    hv += __shfl_xor(hv, 16);
    if (l == 0) out[se.y] = hv + b2s;
  }
}

// ---------------- launch -----------------------------------------------
extern "C" void kernel_launch(void* const* d_in, const int* in_sizes, int n_in,
                              void* d_out, int out_size, void* d_ws, size_t ws_size,
                              hipStream_t stream) {
  const float* x         = (const float*)d_in[0];
  const int*   ei        = (const int*)d_in[1];
  const float* edge_attr = (const float*)d_in[2];
  const float* Wq = (const float*)d_in[3],  *bq = (const float*)d_in[4];
  const float* Wk = (const float*)d_in[5],  *bk = (const float*)d_in[6];
  const float* Wv = (const float*)d_in[7],  *bv = (const float*)d_in[8];
  const float* We = (const float*)d_in[9];
  const float* Wskip = (const float*)d_in[10], *bskip = (const float*)d_in[11];
  const float* W1 = (const float*)d_in[12], *b1 = (const float*)d_in[13];
  const float* W2 = (const float*)d_in[14], *b2 = (const float*)d_in[15];
  float* out = (float*)d_out;

  // workspace (~66 MB); Ah/Cbh ALIAS s_tmp (dead after fine_csr)
  char* w = (char*)d_ws;
  float*   y    = (float*)w;            w += (size_t)NN * 64 * 4;   // 12.8 MB
  float*   qe   = (float*)w;            w += (size_t)NN * 64 * 4;   // 12.8 MB
  float*   u4   = (float*)w;            w += (size_t)NN * 4 * 4;    // 0.8 MB
  int2*    s_se = (int2*)w;             w += (size_t)NE * 8;        // 6.4 MB
  int2*    s_tmp = (int2*)w;            // 6.4 MB (Ah, Cbh alias inside)
  __half*  Ah   = (__half*)s_tmp;                           // 3.2 MB
  __half*  Cbh  = (__half*)((char*)s_tmp + (size_t)NN * 32 * 2); // 3.2 MB
  w += (size_t)NE * 8;
  uint4*   s_ea4 = (uint4*)w;           w += (size_t)NE * 32;       // 25.6 MB
  int*     hist_all = (int*)w;          w += (size_t)NB * HB * 4;   // 627 KB
  int*     btot = (int*)w;              w += 256 * 4;
  int*     coarse_offs = (int*)w;       w += 256 * 4;
  int*     offs = (int*)w;              w += ((size_t)NN + 1) * 4;
  float*   P    = (float*)w;            w += (size_t)P_TOTAL * 4;

  precompute_kernel<<<1, 256, 0, stream>>>(Wq, Wk, bq, bk, We, P);
  node_linear_kernel<<<NODE_BLOCKS + HB, 256, 0, stream>>>(
      x, P, ei, hist_all, y, qe, u4);
  scan_buckets_kernel<<<49, 256, 0, stream>>>(hist_all, btot);
  tiny_scan_kernel<<<1, 256, 0, stream>>>(btot, coarse_offs);
  bucket_scatter_kernel<<<HB, 256, 0, stream>>>(ei, hist_all, coarse_offs,
                                                s_tmp);
  fine_csr_kernel<<<NB, 256, 0, stream>>>(s_tmp, coarse_offs, s_se, offs);
  ea_place_kernel<<<NE / 256, 256, 0, stream>>>(edge_attr, s_se, s_ea4);
  aggregate_kernel<<<NN / 4, 256, 0, stream>>>(y, qe, u4, x,
                                               (const __half*)s_ea4, s_se, P,
                                               We, Wv, bv, Wskip, bskip, W1, b1,
                                               offs, Ah, Cbh);
  mlp_kernel<<<NN / 4, 256, 0, stream>>>(s_se, (const __half*)s_ea4, offs,
                                         Ah, Cbh, W1, W2, b2, out);
}